// Round 3
// baseline (49927.841 us; speedup 1.0000x reference)
//
#include <hip/hip_runtime.h>

// RNNT greedy decode. B=32, T=100, E=512, H=640, 4H=2560, J=640, V=4096 (BLANK).
// rnnt_prep: weight transposes + enc projection + state init (2048 blocks).
// rnnt_decode: 512 blocks = 32 independent groups of 16 (one group per batch).
// Each group runs its own 200-iteration loop with 2 intra-group barriers/iter:
//   phase A: decision(i-1) + LSTM -> h,c      [group barrier]
//   phase B: joint jt (redundant, LDS-only) + output logits + argmax/sumexp slots
//            [group barrier]
// No atomics in the loop; per-block u64 slot stores; u64 fixed-point sumexp is
// order-independent => deterministic. All dots keep serial accumulation order
// (matched reference exactly in rounds 1-2, absmax 0.0).

#define NB 512
#define GPB 16   // blocks per group (= per batch)

__device__ __forceinline__ unsigned f2ord(float f) {
  unsigned u = __float_as_uint(f);
  return (u & 0x80000000u) ? ~u : (u | 0x80000000u);
}
__device__ __forceinline__ float ord2f(unsigned u) {
  return __uint_as_float((u & 0x80000000u) ? (u & 0x7fffffffu) : ~u);
}
__device__ __forceinline__ unsigned long long shfl_xor_u64(unsigned long long x, int m) {
  int lo = __shfl_xor((int)(unsigned)x, m, 64);
  int hi = __shfl_xor((int)(unsigned)(x >> 32), m, 64);
  return ((unsigned long long)(unsigned)hi << 32) | (unsigned)lo;
}

// ---- group barrier: 16 blocks, one padded flag each, everyone polls all ----
__device__ __forceinline__ void gbar(unsigned* __restrict__ arrive, int grp,
                                     int gb, unsigned it) {
  __syncthreads();  // drains each wave's mem ops before s_barrier
  if (threadIdx.x == 0) {
    __threadfence();  // release: write back this XCD's L2 (block's stores are in L2)
    __hip_atomic_store(&arrive[(grp * GPB + gb) * 16], it, __ATOMIC_RELEASE,
                       __HIP_MEMORY_SCOPE_AGENT);
  }
  if (threadIdx.x < GPB) {
    // lanes 0..15 are one wave: loop reconverges only when ALL flags observed
    const unsigned* f = &arrive[(grp * GPB + (int)threadIdx.x) * 16];
    while (__hip_atomic_load(f, __ATOMIC_RELAXED, __HIP_MEMORY_SCOPE_AGENT) < it)
      __builtin_amdgcn_s_sleep(1);
    if (threadIdx.x == 0) __threadfence();  // acquire: invalidate stale L1/L2
  }
  __syncthreads();
}

template <int N>
__device__ __forceinline__ float dotN(const float* __restrict__ a,
                                      const float* __restrict__ b, float acc) {
#pragma unroll 8
  for (int k = 0; k < N; k += 4) {
    float4 av = *(const float4*)(a + k);
    float4 bv = *(const float4*)(b + k);
    acc += av.x * bv.x; acc += av.y * bv.y;
    acc += av.z * bv.z; acc += av.w * bv.w;
  }
  return acc;
}

// ----------------- prep: init + weight transposes + enc projection -----------
__global__ __launch_bounds__(256) void rnnt_prep(
    const float* __restrict__ enc, const float* __restrict__ W_i,
    const float* __restrict__ W_h, const float* __restrict__ W_pred,
    const float* __restrict__ W_out, const float* __restrict__ W_enc,
    const float* __restrict__ b_joint,
    float* __restrict__ out, float* __restrict__ Wcat_t,
    float* __restrict__ Wpred_t, float* __restrict__ Wout_t,
    float* __restrict__ enc_projB, float* __restrict__ h_buf,
    float* __restrict__ c_buf, unsigned* __restrict__ arrive) {
  const int blk = blockIdx.x, tid = threadIdx.x;
  const int gtid = blk * 256 + tid;
  const int GT = gridDim.x * 256;
  __shared__ float s_tr[32][33];

  for (int x = gtid; x < 6464; x += GT) out[x] = (x < 6400) ? 4096.0f : 0.0f;
  for (int x = gtid; x < 40960; x += GT) { h_buf[x] = 0.f; c_buf[x] = 0.f; }
  for (int x = gtid; x < NB * 16; x += GT) arrive[x] = 0u;

  {
    const int NT0 = 1600, NT1 = 1600, NT2 = 400, NT3 = 2580;  // 32x32 tiles
    for (int tl = blk; tl < NT0 + NT1 + NT2 + NT3; tl += gridDim.x) {
      const float* src; float* dst; int C, DS, DO, CT; int tt = tl;
      if (tt < NT0)               { src = W_i;    dst = Wcat_t;  C = 2560; DS = 1280; DO = 0;   CT = 80; }
      else if ((tt -= NT0) < NT1) { src = W_h;    dst = Wcat_t;  C = 2560; DS = 1280; DO = 640; CT = 80; }
      else if ((tt -= NT1) < NT2) { src = W_pred; dst = Wpred_t; C = 640;  DS = 640;  DO = 0;   CT = 20; }
      else { tt -= NT2;             src = W_out;  dst = Wout_t;  C = 4097; DS = 640;  DO = 0;   CT = 129; }
      int rt = tt / CT, ct = tt % CT;
      int r0 = rt * 32, c0 = ct * 32;
      __syncthreads();
#pragma unroll
      for (int p = 0; p < 4; ++p) {
        int rr = (tid >> 5) + 8 * p, cc = tid & 31;
        float v = 0.f;
        if (c0 + cc < C) v = src[(r0 + rr) * C + c0 + cc];
        s_tr[rr][cc] = v;
      }
      __syncthreads();
#pragma unroll
      for (int p = 0; p < 4; ++p) {
        int cc2 = (tid >> 5) + 8 * p, rr2 = tid & 31;
        if (c0 + cc2 < C) dst[(c0 + cc2) * DS + DO + r0 + rr2] = s_tr[rr2][cc2];
      }
    }
  }

  // enc_projB[b][t][j] = sum_e enc[b][e][t] * W_enc[e][j] + b_joint[j]
  for (int idx = gtid; idx < 2048000; idx += GT) {
    int b = idx / 64000, r = idx % 64000;
    int tt = r / 640, j = r % 640;
    const float* ep = enc + b * 51200;
    float acc = b_joint[j];
#pragma unroll 4
    for (int e = 0; e < 512; ++e) acc += ep[e * 100 + tt] * W_enc[e * 640 + j];
    enc_projB[idx] = acc;
  }
}

// ----------------- decode: 32 independent per-batch groups ------------------
__global__ __launch_bounds__(256, 2) void rnnt_decode(
    const int* __restrict__ lens, const float* __restrict__ embed,
    const float* __restrict__ b_lstm, const float* __restrict__ b_out,
    float* __restrict__ out,
    const float* __restrict__ Wcat_t, const float* __restrict__ Wpred_t,
    const float* __restrict__ Wout_t, const float* __restrict__ enc_projB,
    float* __restrict__ h_buf, float* __restrict__ c_buf,
    unsigned long long* __restrict__ kslot, unsigned long long* __restrict__ sslot,
    unsigned* __restrict__ arrive) {
  const int blk = blockIdx.x, tid = threadIdx.x;
  const int grp = blk / GPB;   // batch index b
  const int gb  = blk % GPB;   // block-in-group
  const int b   = grp;

  __shared__ float s_z[4][64];
  __shared__ __align__(16) float s_h[640];
  __shared__ __align__(16) float s_jt[640];
  __shared__ unsigned long long s_rk[4], s_rs[4];

  float* hB = h_buf + b * 1280;
  float* cB = c_buf + b * 1280;
  const int len_b = lens[b];

  // uniform per-thread decoder state (identical in every thread of the group)
  int last_r = 4096, cur_r = 0, cnt_r = 0;
  bool blank_r = false;
  float score_r = 0.f;
  unsigned it = 0;

  for (int i = 0;; ++i) {
    // ---- decision for iteration i-1 (all threads redundantly; uniform) ----
    if (i > 0) {
      int pi = (i - 1) & 1;
      const unsigned long long* kk = kslot + (pi * 32 + b) * 17;
      const unsigned long long* ss = sslot + (pi * 32 + b) * 17;
      unsigned long long key = 0ull, sum = 0ull;
#pragma unroll
      for (int c = 0; c < 17; ++c) {
        unsigned long long kv = kk[c];
        if (kv > key) key = kv;
        sum += ss[c];
      }
      int kArg = 4096 - (int)(key & 0xffffffffu);
      float bl = ord2f((unsigned)(key >> 32));
      float lse = logf((float)sum * 0x1p-32f);
      float vsc = bl - lse;
      int im1 = i - 1, tp = im1 >> 1, sp = im1 & 1;
      bool blank_in = (sp == 0) ? (tp >= len_b) : blank_r;
      bool nb = blank_in || (kArg == 4096);
      blank_r = nb;
      if (!nb) {
        if (gb == 0 && tid == 0) out[b * 200 + cnt_r] = (float)kArg;
        last_r = kArg; cur_r ^= 1; cnt_r++; score_r += vsc;
      }
    }
    if (i == 200) {
      if (gb == 0 && tid == 0) { out[6400 + b] = (float)cnt_r; out[6432 + b] = score_r; }
      return;
    }
    const int t = i >> 1;
    const int nc = cur_r ^ 1;

    // ---- phase A: LSTM z = [x;h] @ [W_i;W_h] + b over 2560 cols ----
    // cols ordered (j,g): cIdx = j*4+g. gb<12: 128 cols, 2-way k-split
    // (half0 = x-dot + bias, half1 = h-dot). gb>=12: 256 cols, full k.
    if (gb < 12) {
      int colL = tid >> 1, half = tid & 1;
      int jl = colL >> 2, g = colL & 3;
      int j = gb * 32 + jl;
      int r = g * 640 + j;
      float acc = (half == 0) ? b_lstm[r] : 0.f;
      if (i > 0) {
        const float* wt = Wcat_t + r * 1280 + half * 640;
        const float* xv = (half == 0) ? (embed + last_r * 640) : (hB + cur_r * 640);
        acc = dotN<640>(wt, xv, acc);
      }
      acc += __shfl_xor(acc, 1, 64);
      if (half == 0) s_z[g][jl] = acc;
    } else {
      int jl = tid >> 2, g = tid & 3;
      int j = 384 + (gb - 12) * 64 + jl;
      int r = g * 640 + j;
      float acc = b_lstm[r];
      if (i > 0) {
        const float* wt = Wcat_t + r * 1280;
        acc = dotN<640>(wt, embed + last_r * 640, acc);
        acc = dotN<640>(wt + 640, hB + cur_r * 640, acc);
      }
      s_z[g][jl] = acc;
    }
    __syncthreads();
    {
      int nj = (gb < 12) ? 32 : 64;
      if (tid < nj) {
        int j = (gb < 12) ? gb * 32 + tid : 384 + (gb - 12) * 64 + tid;
        float zi = s_z[0][tid], zf = s_z[1][tid], zg = s_z[2][tid], zo = s_z[3][tid];
        float cold = cB[cur_r * 640 + j];
        float ig = 1.f / (1.f + expf(-zi));
        float fg = 1.f / (1.f + expf(-zf));
        float og = 1.f / (1.f + expf(-zo));
        float cn = fg * cold + ig * tanhf(zg);
        float hn = og * tanhf(cn);
        hB[nc * 640 + j] = hn;
        cB[nc * 640 + j] = cn;
      }
    }
    gbar(arrive, grp, gb, ++it);

    // ---- phase B: jt = relu(encp + h1 @ W_pred) in LDS, then logits ----
    for (int x = tid; x < 160; x += 256)
      ((float4*)s_h)[x] = *(const float4*)(hB + nc * 640 + x * 4);
    __syncthreads();
    {
      const float* encp = enc_projB + (b * 100 + t) * 640;
      int c0 = tid, c1 = tid + 256;
      float a0 = dotN<640>(Wpred_t + c0 * 640, s_h, 0.f);
      s_jt[c0] = fmaxf(a0 + encp[c0], 0.f);
      float a1 = dotN<640>(Wpred_t + c1 * 640, s_h, 0.f);
      s_jt[c1] = fmaxf(a1 + encp[c1], 0.f);
      if (tid < 128) {
        int c2 = tid + 512;
        float a2 = dotN<640>(Wpred_t + c2 * 640, s_h, 0.f);
        s_jt[c2] = fmaxf(a2 + encp[c2], 0.f);
      }
    }
    __syncthreads();
    // ---- logits col v = gb*256+tid; per-block slot (no atomics) ----
    {
      int p = i & 1;
      int v = gb * 256 + tid;
      float acc = dotN<640>(Wout_t + v * 640, s_jt, b_out[v]);
      unsigned long long key =
          ((unsigned long long)f2ord(acc) << 32) | (unsigned)(4096 - v);
      unsigned long long isum =
          (unsigned long long)(expf(acc) * 4294967296.0f + 0.5f);
      // blank col v=4096: one thread, full-serial dot (order-preserving)
      if (gb == 15 && tid == 255) {
        float aB = dotN<640>(Wout_t + 4096 * 640, s_jt, b_out[4096]);
        kslot[(p * 32 + b) * 17 + 16] = ((unsigned long long)f2ord(aB) << 32);
        sslot[(p * 32 + b) * 17 + 16] =
            (unsigned long long)(expf(aB) * 4294967296.0f + 0.5f);
      }
#pragma unroll
      for (int d = 1; d < 64; d <<= 1) {
        unsigned long long ok = shfl_xor_u64(key, d);
        if (ok > key) key = ok;
        isum += shfl_xor_u64(isum, d);
      }
      int w = tid >> 6;
      if ((tid & 63) == 0) { s_rk[w] = key; s_rs[w] = isum; }
      __syncthreads();
      if (tid == 0) {
        unsigned long long K = s_rk[0], S = s_rs[0];
#pragma unroll
        for (int ww = 1; ww < 4; ++ww) {
          if (s_rk[ww] > K) K = s_rk[ww];
          S += s_rs[ww];
        }
        kslot[(p * 32 + b) * 17 + gb] = K;
        sslot[(p * 32 + b) * 17 + gb] = S;
      }
    }
    gbar(arrive, grp, gb, ++it);
  }
}

extern "C" void kernel_launch(void* const* d_in, const int* in_sizes, int n_in,
                              void* d_out, int out_size, void* d_ws, size_t ws_size,
                              hipStream_t stream) {
  (void)in_sizes; (void)n_in; (void)out_size; (void)ws_size;
  const float* enc    = (const float*)d_in[0];
  const int*   lens   = (const int*)d_in[1];
  const float* embed  = (const float*)d_in[2];
  const float* W_i    = (const float*)d_in[3];
  const float* W_h    = (const float*)d_in[4];
  const float* b_lstm = (const float*)d_in[5];
  const float* W_enc  = (const float*)d_in[6];
  const float* W_pred = (const float*)d_in[7];
  const float* b_joint= (const float*)d_in[8];
  const float* W_out  = (const float*)d_in[9];
  const float* b_out  = (const float*)d_in[10];
  float* out = (float*)d_out;

  char* ws = (char*)d_ws;
  size_t off = 0;
  auto carve = [&](size_t bytes) -> void* {
    void* p = ws + off;
    off += (bytes + 255) & ~(size_t)255;
    return p;
  };
  unsigned* arrive           = (unsigned*)carve((size_t)NB * 16 * 4);
  unsigned long long* kslot  = (unsigned long long*)carve(2 * 32 * 17 * 8);
  unsigned long long* sslot  = (unsigned long long*)carve(2 * 32 * 17 * 8);
  float* h_buf    = (float*)carve((size_t)32 * 2 * 640 * 4);
  float* c_buf    = (float*)carve((size_t)32 * 2 * 640 * 4);
  float* Wpred_t  = (float*)carve((size_t)640 * 640 * 4);
  float* Wcat_t   = (float*)carve((size_t)2560 * 1280 * 4);
  float* Wout_t   = (float*)carve((size_t)4097 * 640 * 4);
  float* enc_projB= (float*)carve((size_t)32 * 100 * 640 * 4);

  rnnt_prep<<<2048, 256, 0, stream>>>(
      enc, W_i, W_h, W_pred, W_out, W_enc, b_joint,
      out, Wcat_t, Wpred_t, Wout_t, enc_projB, h_buf, c_buf, arrive);
  rnnt_decode<<<NB, 256, 0, stream>>>(
      lens, embed, b_lstm, b_out, out,
      Wcat_t, Wpred_t, Wout_t, enc_projB, h_buf, c_buf, kslot, sslot, arrive);
}

// Round 4
// 24369.423 us; speedup vs baseline: 2.0488x; 2.0488x over previous
//
#include <hip/hip_runtime.h>

// RNNT greedy decode. B=32, T=100, E=512, H=640, 4H=2560, J=640, V=4096 (BLANK).
// Batch-shared persistent decode (weights read once per iteration), 512 blocks.
// Cross-block sync: coherent (sc0 sc1) flag stores/polls, master fan-out, no
// __threadfence (no L2 writeback/invalidate in the loop).
// Mutable data (h, jt, argmax slots) exchanged via iteration-indexed rings:
// producers write-through to the coherence point; consumers read cold addresses
// with normal cached loads (L2-amortized per XCD). c-state lives in registers.

#define NB 512
#define S1B 320            // blocks doing LSTM + joint (2 j-columns each)
#define HRS 20480          // 32*640 floats per ring slot

__device__ __forceinline__ unsigned f2ord(float f) {
  unsigned u = __float_as_uint(f);
  return (u & 0x80000000u) ? ~u : (u | 0x80000000u);
}
__device__ __forceinline__ float ord2f(unsigned u) {
  return __uint_as_float((u & 0x80000000u) ? (u & 0x7fffffffu) : ~u);
}
__device__ __forceinline__ unsigned long long shfl_xor_u64(unsigned long long x, int m) {
  int lo = __shfl_xor((int)(unsigned)x, m, 64);
  int hi = __shfl_xor((int)(unsigned)(x >> 32), m, 64);
  return ((unsigned long long)(unsigned)hi << 32) | (unsigned)lo;
}

// ---- coherence-point accesses (bypass L1/L2; no cache maintenance ops) ----
__device__ __forceinline__ void st_coh_f32(float* p, float v) {
  asm volatile("global_store_dword %0, %1, off sc0 sc1" :: "v"(p), "v"(v) : "memory");
}
__device__ __forceinline__ void st_coh_u32(unsigned* p, unsigned v) {
  asm volatile("global_store_dword %0, %1, off sc0 sc1" :: "v"(p), "v"(v) : "memory");
}
__device__ __forceinline__ unsigned ld_coh_u32(const unsigned* p) {
  unsigned r;
  asm volatile("global_load_dword %0, %1, off sc0 sc1\n\ts_waitcnt vmcnt(0)"
               : "=v"(r) : "v"(p) : "memory");
  return r;
}
__device__ __forceinline__ unsigned long long ld_coh_u64(const unsigned long long* p) {
  unsigned long long r;
  asm volatile("global_load_dwordx2 %0, %1, off sc0 sc1\n\ts_waitcnt vmcnt(0)"
               : "=v"(r) : "v"(p) : "memory");
  return r;
}

// ---- global barrier: coherent flags, master (block 0) fan-out --------------
__device__ __forceinline__ void gbarrier(unsigned* __restrict__ arrive,
                                         unsigned* __restrict__ go, unsigned it) {
  const int blk = blockIdx.x, tid = threadIdx.x;
  __syncthreads();  // compiler drains vmcnt before s_barrier -> stores done
  if (blk == 0) {
    for (int f = 1 + tid; f < NB; f += 256) {
      while (ld_coh_u32(arrive + f * 4) < it) __builtin_amdgcn_s_sleep(1);
    }
    __syncthreads();
    if (tid < 64) st_coh_u32(go + tid * 4, it);
    __syncthreads();
  } else {
    if (tid == 0) {
      st_coh_u32(arrive + blk * 4, it);
      while (ld_coh_u32(go + (blk & 63) * 4) < it) __builtin_amdgcn_s_sleep(1);
    }
    __syncthreads();
  }
}

template <int N>
__device__ __forceinline__ float dot4(const float* __restrict__ a,
                                      const float* __restrict__ b) {
  float a0 = 0.f, a1 = 0.f, a2 = 0.f, a3 = 0.f;
#pragma unroll 8
  for (int k = 0; k < N; k += 4) {
    float4 av = *(const float4*)(a + k);
    float4 bv = *(const float4*)(b + k);
    a0 += av.x * bv.x; a1 += av.y * bv.y;
    a2 += av.z * bv.z; a3 += av.w * bv.w;
  }
  return (a0 + a1) + (a2 + a3);
}

// ----------------- prep: init + weight transposes + enc projection ----------
__global__ __launch_bounds__(256) void rnnt_prep(
    const float* __restrict__ enc, const float* __restrict__ W_i,
    const float* __restrict__ W_h, const float* __restrict__ W_pred,
    const float* __restrict__ W_out, const float* __restrict__ W_enc,
    const float* __restrict__ b_joint,
    float* __restrict__ out, float* __restrict__ Wcat_t,
    float* __restrict__ Wpred_t, float* __restrict__ Wout_t,
    float* __restrict__ enc_projB, float* __restrict__ h_ring,
    unsigned long long* __restrict__ kslot, unsigned long long* __restrict__ sslot,
    unsigned* __restrict__ arrive, unsigned* __restrict__ go) {
  const int blk = blockIdx.x, tid = threadIdx.x;
  const int gtid = blk * 256 + tid;
  const int GT = gridDim.x * 256;
  __shared__ float s_tr[32][33];

  for (int x = gtid; x < 6464; x += GT) out[x] = (x < 6400) ? 4096.0f : 0.0f;
  for (int x = gtid; x < HRS; x += GT) h_ring[(size_t)200 * HRS + x] = 0.f;
  for (int x = gtid; x < 51200; x += GT) { kslot[x] = 0ull; sslot[x] = 0ull; }
  for (int x = gtid; x < NB * 4; x += GT) arrive[x] = 0u;
  for (int x = gtid; x < 64 * 4; x += GT) go[x] = 0u;

  {
    const int NT0 = 1600, NT1 = 1600, NT2 = 400, NT3 = 2580;  // 32x32 tiles
    for (int tl = blk; tl < NT0 + NT1 + NT2 + NT3; tl += gridDim.x) {
      const float* src; float* dst; int C, DS, DO, CT; int tt = tl;
      if (tt < NT0)               { src = W_i;    dst = Wcat_t;  C = 2560; DS = 1280; DO = 0;   CT = 80; }
      else if ((tt -= NT0) < NT1) { src = W_h;    dst = Wcat_t;  C = 2560; DS = 1280; DO = 640; CT = 80; }
      else if ((tt -= NT1) < NT2) { src = W_pred; dst = Wpred_t; C = 640;  DS = 640;  DO = 0;   CT = 20; }
      else { tt -= NT2;             src = W_out;  dst = Wout_t;  C = 4097; DS = 640;  DO = 0;   CT = 129; }
      int rt = tt / CT, ct = tt % CT;
      int r0 = rt * 32, c0 = ct * 32;
      __syncthreads();
#pragma unroll
      for (int p = 0; p < 4; ++p) {
        int rr = (tid >> 5) + 8 * p, cc = tid & 31;
        float v = 0.f;
        if (c0 + cc < C) v = src[(r0 + rr) * C + c0 + cc];
        s_tr[rr][cc] = v;
      }
      __syncthreads();
#pragma unroll
      for (int p = 0; p < 4; ++p) {
        int cc2 = (tid >> 5) + 8 * p, rr2 = tid & 31;
        if (c0 + cc2 < C) dst[(c0 + cc2) * DS + DO + r0 + rr2] = s_tr[rr2][cc2];
      }
    }
  }

  // enc_projB[b][t][j] = sum_e enc[b][e][t] * W_enc[e][j] + b_joint[j]
  for (int idx = gtid; idx < 2048000; idx += GT) {
    int b = idx / 64000, r = idx % 64000;
    int tt = r / 640, j = r % 640;
    const float* ep = enc + b * 51200;
    float acc = b_joint[j];
#pragma unroll 4
    for (int e = 0; e < 512; ++e) acc += ep[e * 100 + tt] * W_enc[e * 640 + j];
    enc_projB[idx] = acc;
  }
}

// ----------------- decode: persistent, batch-shared, 512 blocks -------------
__global__ __launch_bounds__(256, 2) void rnnt_decode(
    const int* __restrict__ lens, const float* __restrict__ embed,
    const float* __restrict__ b_lstm, const float* __restrict__ b_out,
    float* __restrict__ out,
    const float* __restrict__ Wcat_t, const float* __restrict__ Wpred_t,
    const float* __restrict__ Wout_t, const float* __restrict__ enc_projB,
    float* __restrict__ h_ring, float* __restrict__ jt_ring,
    unsigned long long* __restrict__ kslot, unsigned long long* __restrict__ sslot,
    unsigned* __restrict__ arrive, unsigned* __restrict__ go) {
  const int blk = blockIdx.x, tid = threadIdx.x;

  __shared__ float s_zp[2][4][32][2];
  __shared__ float s_red[4][64];
  __shared__ unsigned long long s_dk[32], s_ds[32];
  __shared__ int s_last[32], s_hsrc[32], s_commit[32];

  // per-lane decoder state (lanes 0..31 track batch=lane, in EVERY block)
  int last_r = 4096, hsrc_r = 200, cnt_r = 0;
  bool blank_r = false;
  float score_r = 0.f;
  // per-thread LSTM cell state (tid<64 of S1 blocks: b=tid>>1, j=blk*2+(tid&1))
  float c_comm = 0.f, c_cand = 0.f;
  unsigned it = 0;
  const int len_b = lens[tid & 31];

  for (int i = 0;; ++i) {
    // ---- combine argmax/sumexp slots of iter i-1 (all 256 threads) ----
    if (i > 0) {
      int ip = i - 1;
      int b8 = tid >> 3, sl = tid & 7;
      unsigned long long kv = ld_coh_u64(kslot + ((size_t)ip * 32 + b8) * 8 + sl);
      unsigned long long sv = ld_coh_u64(sslot + ((size_t)ip * 32 + b8) * 8 + sl);
#pragma unroll
      for (int d = 1; d < 8; d <<= 1) {
        unsigned long long ok = shfl_xor_u64(kv, d);
        if (ok > kv) kv = ok;
        sv += shfl_xor_u64(sv, d);
      }
      if (sl == 0) { s_dk[b8] = kv; s_ds[b8] = sv; }
    }
    __syncthreads();
    if (tid < 32) {
      int b = tid;
      int cm = 0;
      if (i > 0) {
        unsigned long long key = s_dk[b], sum = s_ds[b];
        int kArg = 4096 - (int)(key & 0xffffffffu);
        float bl = ord2f((unsigned)(key >> 32));
        float lse = logf((float)sum * 0x1p-32f);
        float vsc = bl - lse;
        int im1 = i - 1, tp = im1 >> 1, sp = im1 & 1;
        bool blank_in = (sp == 0) ? (tp >= len_b) : blank_r;
        bool nb = blank_in || (kArg == 4096);
        blank_r = nb;
        if (!nb) {
          if (blk == b) out[b * 200 + cnt_r] = (float)kArg;
          last_r = kArg; hsrc_r = im1; cnt_r++; score_r += vsc; cm = 1;
        }
      }
      if (i == 200 && blk == b) { out[6400 + b] = (float)cnt_r; out[6432 + b] = score_r; }
      s_last[b] = last_r; s_hsrc[b] = hsrc_r; s_commit[b] = cm;
    }
    __syncthreads();
    if (i == 200) return;
    const int t = i >> 1;

    // ---- stage 1: LSTM z = [x;h]@[W_i;W_h]+b. K-halved: half0=x+bias, half1=h
    if (blk < S1B) {
      const int b = tid & 31;
      const int g = (tid >> 5) & 3;
      const int half = tid >> 7;
      const int j0 = blk * 2;
      float a0 = 0.f, a1 = 0.f, a2 = 0.f, a3 = 0.f;
      float b0 = 0.f, b1 = 0.f, b2 = 0.f, b3 = 0.f;
      if (i > 0) {
        const float* w0 = Wcat_t + ((size_t)(g * 640 + j0)) * 1280 + half * 640;
        const float* w1 = w0 + 1280;
        const float* xr = (half == 0) ? (embed + (size_t)s_last[b] * 640)
                                      : (h_ring + (size_t)s_hsrc[b] * HRS + b * 640);
#pragma unroll 4
        for (int k = 0; k < 640; k += 4) {
          float4 xv = *(const float4*)(xr + k);
          float4 wa = *(const float4*)(w0 + k);
          float4 wb = *(const float4*)(w1 + k);
          a0 += wa.x * xv.x; a1 += wa.y * xv.y; a2 += wa.z * xv.z; a3 += wa.w * xv.w;
          b0 += wb.x * xv.x; b1 += wb.y * xv.y; b2 += wb.z * xv.z; b3 += wb.w * xv.w;
        }
      }
      float z0 = (a0 + a1) + (a2 + a3);
      float z1 = (b0 + b1) + (b2 + b3);
      if (half == 0) { z0 += b_lstm[g * 640 + j0]; z1 += b_lstm[g * 640 + j0 + 1]; }
      s_zp[half][g][b][0] = z0;
      s_zp[half][g][b][1] = z1;
    }
    __syncthreads();
    if (blk < S1B && tid < 64) {
      const int b = tid >> 1, j_l = tid & 1;
      float zi = s_zp[0][0][b][j_l] + s_zp[1][0][b][j_l];
      float zf = s_zp[0][1][b][j_l] + s_zp[1][1][b][j_l];
      float zg = s_zp[0][2][b][j_l] + s_zp[1][2][b][j_l];
      float zo = s_zp[0][3][b][j_l] + s_zp[1][3][b][j_l];
      if (s_commit[b]) c_comm = c_cand;  // advance committed cell state
      float ig = 1.f / (1.f + expf(-zi));
      float fg = 1.f / (1.f + expf(-zf));
      float og = 1.f / (1.f + expf(-zo));
      float cn = fg * c_comm + ig * tanhf(zg);
      float hn = og * tanhf(cn);
      c_cand = cn;
      st_coh_f32(&h_ring[(size_t)i * HRS + b * 640 + blk * 2 + j_l], hn);
    }
    gbarrier(arrive, go, ++it);

    // ---- stage 3: jt = relu(enc_projB[:,t] + h1 @ W_pred) ----
    if (blk < S1B) {
      const int w = tid >> 6, lane = tid & 63, b = lane >> 1, j_l = lane & 1;
      const int j = blk * 2 + j_l;
      const float* h1 = h_ring + (size_t)i * HRS + b * 640 + w * 160;
      const float* wp = Wpred_t + (size_t)j * 640 + w * 160;
      s_red[w][lane] = dot4<160>(wp, h1);
    }
    __syncthreads();
    if (blk < S1B && tid < 64) {
      const int b = tid >> 1, j_l = tid & 1, j = blk * 2 + j_l;
      float sm = (s_red[0][tid] + s_red[1][tid]) + (s_red[2][tid] + s_red[3][tid]);
      float val = enc_projB[(b * 100 + t) * 640 + j] + sm;
      st_coh_f32(&jt_ring[(size_t)i * HRS + b * 640 + j], fmaxf(val, 0.f));
    }
    gbarrier(arrive, go, ++it);

    // ---- stage 4: logits = jt @ W_out + b_out; argmax + fixed-point sumexp --
    {
      const int b = tid >> 3, v_l = tid & 7;
      const int v = blk * 8 + v_l;  // 0..4095
      const float* jr = jt_ring + (size_t)i * HRS + b * 640;
      float acc = dot4<640>(Wout_t + (size_t)v * 640, jr) + b_out[v];
      unsigned long long key =
          ((unsigned long long)f2ord(acc) << 32) | (unsigned)(4096 - v);
      unsigned long long isum =
          (unsigned long long)(expf(acc) * 4294967296.0f + 0.5f);
#pragma unroll
      for (int d = 1; d < 8; d <<= 1) {
        unsigned long long ok = shfl_xor_u64(key, d);
        if (ok > key) key = ok;
        isum += shfl_xor_u64(isum, d);
      }
      if (v_l == 0) {
        atomicMax(&kslot[((size_t)i * 32 + b) * 8 + (blk & 7)], key);
        atomicAdd(&sslot[((size_t)i * 32 + b) * 8 + (blk & 7)], isum);
      }
      if (blk == NB - 1) {  // BLANK column v=4096, K-split 8 ways per batch
        const int kq = v_l;
        float part = dot4<80>(Wout_t + (size_t)4096 * 640 + kq * 80, jr + kq * 80);
#pragma unroll
        for (int d = 1; d < 8; d <<= 1) part += __shfl_xor(part, d, 64);
        if (kq == 0) {
          float aB = part + b_out[4096];
          unsigned long long key2 = ((unsigned long long)f2ord(aB) << 32);
          unsigned long long is2 =
              (unsigned long long)(expf(aB) * 4294967296.0f + 0.5f);
          atomicMax(&kslot[((size_t)i * 32 + b) * 8 + 7], key2);
          atomicAdd(&sslot[((size_t)i * 32 + b) * 8 + 7], is2);
        }
      }
    }
    gbarrier(arrive, go, ++it);
  }
}

extern "C" void kernel_launch(void* const* d_in, const int* in_sizes, int n_in,
                              void* d_out, int out_size, void* d_ws, size_t ws_size,
                              hipStream_t stream) {
  (void)in_sizes; (void)n_in; (void)out_size; (void)ws_size;
  const float* enc    = (const float*)d_in[0];
  const int*   lens   = (const int*)d_in[1];
  const float* embed  = (const float*)d_in[2];
  const float* W_i    = (const float*)d_in[3];
  const float* W_h    = (const float*)d_in[4];
  const float* b_lstm = (const float*)d_in[5];
  const float* W_enc  = (const float*)d_in[6];
  const float* W_pred = (const float*)d_in[7];
  const float* b_joint= (const float*)d_in[8];
  const float* W_out  = (const float*)d_in[9];
  const float* b_out  = (const float*)d_in[10];
  float* out = (float*)d_out;

  char* ws = (char*)d_ws;
  size_t off = 0;
  auto carve = [&](size_t bytes) -> void* {
    void* p = ws + off;
    off += (bytes + 255) & ~(size_t)255;
    return p;
  };
  unsigned* arrive           = (unsigned*)carve((size_t)NB * 4 * 4);
  unsigned* go               = (unsigned*)carve((size_t)64 * 4 * 4);
  unsigned long long* kslot  = (unsigned long long*)carve((size_t)51200 * 8);
  unsigned long long* sslot  = (unsigned long long*)carve((size_t)51200 * 8);
  float* h_ring   = (float*)carve((size_t)201 * HRS * 4);
  float* jt_ring  = (float*)carve((size_t)200 * HRS * 4);
  float* Wpred_t  = (float*)carve((size_t)640 * 640 * 4);
  float* Wcat_t   = (float*)carve((size_t)2560 * 1280 * 4);
  float* Wout_t   = (float*)carve((size_t)4097 * 640 * 4);
  float* enc_projB= (float*)carve((size_t)32 * 100 * 640 * 4);

  rnnt_prep<<<2048, 256, 0, stream>>>(
      enc, W_i, W_h, W_pred, W_out, W_enc, b_joint,
      out, Wcat_t, Wpred_t, Wout_t, enc_projB, h_ring, kslot, sslot, arrive, go);
  rnnt_decode<<<NB, 256, 0, stream>>>(
      lens, embed, b_lstm, b_out, out,
      Wcat_t, Wpred_t, Wout_t, enc_projB, h_ring, jt_ring, kslot, sslot,
      arrive, go);
}

// Round 5
// 15699.934 us; speedup vs baseline: 3.1801x; 1.5522x over previous
//
#include <hip/hip_runtime.h>

// RNNT greedy decode. B=32, T=100, E=512, H=640, 4H=2560, J=640, V=4096 (BLANK).
// Batch-shared persistent decode (weights read once per iteration), 512 blocks.
// v5: (a) decision-phase slot reads use plain cached loads (cold lines) instead
// of 262K coherent loads/iter; (b) x/h/jt row-gathers staged through a 40KB
// XOR-swizzled LDS tile with coalesced loads; (c) W_out re-laid k-major
// interleaved [k/4][4097][4] so stage-4 weight loads are 2 lines/instr.
// All dot products keep round-4's 4-chain ascending-k accumulation order.

#define NB 512
#define S1B 320            // blocks doing LSTM + joint (2 j-columns each)
#define HRS 20480          // 32*640 floats per ring slot

__device__ __forceinline__ unsigned f2ord(float f) {
  unsigned u = __float_as_uint(f);
  return (u & 0x80000000u) ? ~u : (u | 0x80000000u);
}
__device__ __forceinline__ float ord2f(unsigned u) {
  return __uint_as_float((u & 0x80000000u) ? (u & 0x7fffffffu) : ~u);
}
__device__ __forceinline__ unsigned long long shfl_xor_u64(unsigned long long x, int m) {
  int lo = __shfl_xor((int)(unsigned)x, m, 64);
  int hi = __shfl_xor((int)(unsigned)(x >> 32), m, 64);
  return ((unsigned long long)(unsigned)hi << 32) | (unsigned)lo;
}

// ---- coherence-point accesses (flags + cross-block produced data) ----------
__device__ __forceinline__ void st_coh_f32(float* p, float v) {
  asm volatile("global_store_dword %0, %1, off sc0 sc1" :: "v"(p), "v"(v) : "memory");
}
__device__ __forceinline__ void st_coh_u32(unsigned* p, unsigned v) {
  asm volatile("global_store_dword %0, %1, off sc0 sc1" :: "v"(p), "v"(v) : "memory");
}
__device__ __forceinline__ unsigned ld_coh_u32(const unsigned* p) {
  unsigned r;
  asm volatile("global_load_dword %0, %1, off sc0 sc1\n\ts_waitcnt vmcnt(0)"
               : "=v"(r) : "v"(p) : "memory");
  return r;
}

// ---- global barrier: coherent flags, master (block 0) fan-out --------------
__device__ __forceinline__ void gbarrier(unsigned* __restrict__ arrive,
                                         unsigned* __restrict__ go, unsigned it) {
  const int blk = blockIdx.x, tid = threadIdx.x;
  __syncthreads();  // drains vmcnt per wave -> stores/atomics complete
  if (blk == 0) {
    for (int f = 1 + tid; f < NB; f += 256) {
      while (ld_coh_u32(arrive + f * 4) < it) __builtin_amdgcn_s_sleep(1);
    }
    __syncthreads();
    if (tid < 64) st_coh_u32(go + tid * 4, it);
    __syncthreads();
  } else {
    if (tid == 0) {
      st_coh_u32(arrive + blk * 4, it);
      while (ld_coh_u32(go + (blk & 63) * 4) < it) __builtin_amdgcn_s_sleep(1);
    }
    __syncthreads();
  }
}

// ---- LDS tile: 32 rows x 320 floats, XOR-swizzled 16B chunks ---------------
__device__ __forceinline__ void stage_tile(float (*__restrict__ t)[320],
                                           const float* __restrict__ src_row,
                                           int rb, int q) {
#pragma unroll
  for (int p = 0; p < 10; ++p) {
    int c = q + (p << 3);
    float4 v = *(const float4*)(src_row + (c << 2));
    *(float4*)&t[rb][(c ^ (rb & 7)) << 2] = v;
  }
}
__device__ __forceinline__ float4 tile_read(const float (*__restrict__ t)[320],
                                            int b, int c) {
  return *(const float4*)&t[b][(c ^ (b & 7)) << 2];
}

// ----------------- prep: init + weight relayouts + enc projection -----------
__global__ __launch_bounds__(256) void rnnt_prep(
    const float* __restrict__ enc, const float* __restrict__ W_i,
    const float* __restrict__ W_h, const float* __restrict__ W_pred,
    const float* __restrict__ W_out, const float* __restrict__ W_enc,
    const float* __restrict__ b_joint,
    float* __restrict__ out, float* __restrict__ Wcat_t,
    float* __restrict__ Wpred_t, float* __restrict__ Wout_k4,
    float* __restrict__ enc_projB, float* __restrict__ h_ring,
    unsigned long long* __restrict__ kslot, unsigned long long* __restrict__ sslot,
    unsigned* __restrict__ arrive, unsigned* __restrict__ go) {
  const int blk = blockIdx.x, tid = threadIdx.x;
  const int gtid = blk * 256 + tid;
  const int GT = gridDim.x * 256;
  __shared__ float s_tr[32][33];

  for (int x = gtid; x < 6464; x += GT) out[x] = (x < 6400) ? 4096.0f : 0.0f;
  for (int x = gtid; x < HRS; x += GT) h_ring[(size_t)200 * HRS + x] = 0.f;
  for (int x = gtid; x < 51200; x += GT) { kslot[x] = 0ull; sslot[x] = 0ull; }
  for (int x = gtid; x < NB * 4; x += GT) arrive[x] = 0u;
  for (int x = gtid; x < 64 * 4; x += GT) go[x] = 0u;

  {
    const int NT0 = 1600, NT1 = 1600, NT2 = 400;  // 32x32 tiles
    for (int tl = blk; tl < NT0 + NT1 + NT2; tl += gridDim.x) {
      const float* src; float* dst; int C, DS, DO, CT; int tt = tl;
      if (tt < NT0)               { src = W_i;    dst = Wcat_t;  C = 2560; DS = 1280; DO = 0;   CT = 80; }
      else if ((tt -= NT0) < NT1) { src = W_h;    dst = Wcat_t;  C = 2560; DS = 1280; DO = 640; CT = 80; }
      else { tt -= NT1;             src = W_pred; dst = Wpred_t; C = 640;  DS = 640;  DO = 0;   CT = 20; }
      int rt = tt / CT, ct = tt % CT;
      int r0 = rt * 32, c0 = ct * 32;
      __syncthreads();
#pragma unroll
      for (int p = 0; p < 4; ++p) {
        int rr = (tid >> 5) + 8 * p, cc = tid & 31;
        s_tr[rr][cc] = src[(r0 + rr) * C + c0 + cc];
      }
      __syncthreads();
#pragma unroll
      for (int p = 0; p < 4; ++p) {
        int cc2 = (tid >> 5) + 8 * p, rr2 = tid & 31;
        dst[(c0 + cc2) * DS + DO + r0 + rr2] = s_tr[rr2][cc2];
      }
    }
  }

  // Wout_k4[k4][v][e] = W_out[4*k4+e][v]   (160 x 4097 x 4)
  for (int g = gtid; g < 160 * 4097; g += GT) {
    int k4 = g / 4097, v = g - k4 * 4097;
    float4 o;
    o.x = W_out[(size_t)(4 * k4 + 0) * 4097 + v];
    o.y = W_out[(size_t)(4 * k4 + 1) * 4097 + v];
    o.z = W_out[(size_t)(4 * k4 + 2) * 4097 + v];
    o.w = W_out[(size_t)(4 * k4 + 3) * 4097 + v];
    ((float4*)Wout_k4)[g] = o;
  }

  // enc_projB[b][t][j] = sum_e enc[b][e][t] * W_enc[e][j] + b_joint[j]
  for (int idx = gtid; idx < 2048000; idx += GT) {
    int b = idx / 64000, r = idx % 64000;
    int tt = r / 640, j = r % 640;
    const float* ep = enc + b * 51200;
    float acc = b_joint[j];
#pragma unroll 4
    for (int e = 0; e < 512; ++e) acc += ep[e * 100 + tt] * W_enc[e * 640 + j];
    enc_projB[idx] = acc;
  }
}

// ----------------- decode: persistent, batch-shared, 512 blocks -------------
__global__ __launch_bounds__(256, 2) void rnnt_decode(
    const int* __restrict__ lens, const float* __restrict__ embed,
    const float* __restrict__ b_lstm, const float* __restrict__ b_out,
    float* __restrict__ out,
    const float* __restrict__ Wcat_t, const float* __restrict__ Wpred_t,
    const float* __restrict__ Wout_k4, const float* __restrict__ enc_projB,
    float* __restrict__ h_ring, float* __restrict__ jt_ring,
    unsigned long long* __restrict__ kslot, unsigned long long* __restrict__ sslot,
    unsigned* __restrict__ arrive, unsigned* __restrict__ go) {
  const int blk = blockIdx.x, tid = threadIdx.x;

  __shared__ float s_tile[32][320];           // 40KB staging tile (swizzled)
  __shared__ float s_zp[2][4][32][2];
  __shared__ float s_red[4][64];
  __shared__ unsigned long long s_dk[32], s_ds[32];
  __shared__ int s_last[32], s_hsrc[32], s_commit[32];

  // per-lane decoder state (lanes 0..31 track batch=lane, in EVERY block)
  int last_r = 4096, hsrc_r = 200, cnt_r = 0;
  bool blank_r = false;
  float score_r = 0.f;
  // per-thread LSTM cell state (tid<64 of S1 blocks: b=tid>>1, j=blk*2+(tid&1))
  float c_comm = 0.f, c_cand = 0.f;
  unsigned it = 0;
  const int len_b = lens[tid & 31];

  for (int i = 0;; ++i) {
    // ---- combine argmax/sumexp slots of iter i-1 (plain cached loads) ----
    if (i > 0) {
      int ip = i - 1;
      int b8 = tid >> 3, sl = tid & 7;
      unsigned long long kv = kslot[((size_t)ip * 32 + b8) * 8 + sl];
      unsigned long long sv = sslot[((size_t)ip * 32 + b8) * 8 + sl];
#pragma unroll
      for (int d = 1; d < 8; d <<= 1) {
        unsigned long long ok = shfl_xor_u64(kv, d);
        if (ok > kv) kv = ok;
        sv += shfl_xor_u64(sv, d);
      }
      if (sl == 0) { s_dk[b8] = kv; s_ds[b8] = sv; }
    }
    __syncthreads();
    if (tid < 32) {
      int b = tid;
      int cm = 0;
      if (i > 0) {
        unsigned long long key = s_dk[b], sum = s_ds[b];
        int kArg = 4096 - (int)(key & 0xffffffffu);
        float bl = ord2f((unsigned)(key >> 32));
        float lse = logf((float)sum * 0x1p-32f);
        float vsc = bl - lse;
        int im1 = i - 1, tp = im1 >> 1, sp = im1 & 1;
        bool blank_in = (sp == 0) ? (tp >= len_b) : blank_r;
        bool nb = blank_in || (kArg == 4096);
        blank_r = nb;
        if (!nb) {
          if (blk == b) out[b * 200 + cnt_r] = (float)kArg;
          last_r = kArg; hsrc_r = im1; cnt_r++; score_r += vsc; cm = 1;
        }
      }
      if (i == 200 && blk == b) { out[6400 + b] = (float)cnt_r; out[6432 + b] = score_r; }
      s_last[b] = last_r; s_hsrc[b] = hsrc_r; s_commit[b] = cm;
    }
    __syncthreads();
    if (i == 200) return;
    const int t = i >> 1;

    // ---- stage 1: LSTM z = [x;h]@[W_i;W_h]+b via LDS tiles ----
    if (blk < S1B) {
      const int b = tid & 31;
      const int g = (tid >> 5) & 3;
      const int half = tid >> 7;
      const int j0 = blk * 2;
      float a0 = 0.f, a1 = 0.f, a2 = 0.f, a3 = 0.f;
      float e0 = 0.f, e1 = 0.f, e2 = 0.f, e3 = 0.f;
      if (i > 0) {
        const int rb = tid >> 3, q = tid & 7;
#pragma unroll 1
        for (int tt = 0; tt < 4; ++tt) {  // tiles 0,1 = x; 2,3 = h_prev
          const float* src = (tt < 2)
              ? embed + (size_t)s_last[rb] * 640 + tt * 320
              : h_ring + (size_t)s_hsrc[rb] * HRS + rb * 640 + (tt - 2) * 320;
          stage_tile(s_tile, src, rb, q);
          __syncthreads();
          if ((tt >> 1) == half) {
            const float* wr = Wcat_t + (size_t)(g * 640 + j0) * 1280 +
                              half * 640 + (tt & 1) * 320;
            const float* wr2 = wr + 1280;
#pragma unroll 8
            for (int cc = 0; cc < 80; ++cc) {
              float4 xv = tile_read(s_tile, b, cc);
              float4 wa = *(const float4*)(wr + cc * 4);
              float4 wb = *(const float4*)(wr2 + cc * 4);
              a0 += wa.x * xv.x; a1 += wa.y * xv.y;
              a2 += wa.z * xv.z; a3 += wa.w * xv.w;
              e0 += wb.x * xv.x; e1 += wb.y * xv.y;
              e2 += wb.z * xv.z; e3 += wb.w * xv.w;
            }
          }
          __syncthreads();
        }
      }
      float z0 = (a0 + a1) + (a2 + a3);
      float z1 = (e0 + e1) + (e2 + e3);
      if (half == 0) { z0 += b_lstm[g * 640 + j0]; z1 += b_lstm[g * 640 + j0 + 1]; }
      s_zp[half][g][b][0] = z0;
      s_zp[half][g][b][1] = z1;
    }
    __syncthreads();
    if (blk < S1B && tid < 64) {
      const int b = tid >> 1, j_l = tid & 1;
      float zi = s_zp[0][0][b][j_l] + s_zp[1][0][b][j_l];
      float zf = s_zp[0][1][b][j_l] + s_zp[1][1][b][j_l];
      float zg = s_zp[0][2][b][j_l] + s_zp[1][2][b][j_l];
      float zo = s_zp[0][3][b][j_l] + s_zp[1][3][b][j_l];
      if (s_commit[b]) c_comm = c_cand;  // advance committed cell state
      float ig = 1.f / (1.f + expf(-zi));
      float fg = 1.f / (1.f + expf(-zf));
      float og = 1.f / (1.f + expf(-zo));
      float cn = fg * c_comm + ig * tanhf(zg);
      float hn = og * tanhf(cn);
      c_cand = cn;
      st_coh_f32(&h_ring[(size_t)i * HRS + b * 640 + blk * 2 + j_l], hn);
    }
    gbarrier(arrive, go, ++it);

    // ---- stage 3: jt = relu(enc_projB[:,t] + h1 @ W_pred) via LDS tiles ----
    if (blk < S1B) {
      const int w = tid >> 6, lane = tid & 63, bb = lane >> 1, j_l = lane & 1;
      const int j = blk * 2 + j_l;
      const int rb = tid >> 3, q = tid & 7;
      float r0 = 0.f, r1 = 0.f, r2 = 0.f, r3 = 0.f;
#pragma unroll 1
      for (int tt = 0; tt < 2; ++tt) {
        const float* src = h_ring + (size_t)i * HRS + rb * 640 + tt * 320;
        stage_tile(s_tile, src, rb, q);
        __syncthreads();
        if ((w >> 1) == tt) {
          const float* wp = Wpred_t + (size_t)j * 640 + w * 160;
          const int c0 = (w & 1) * 40;
#pragma unroll 8
          for (int cc = 0; cc < 40; ++cc) {
            float4 hv = tile_read(s_tile, bb, c0 + cc);
            float4 wv = *(const float4*)(wp + cc * 4);
            r0 += wv.x * hv.x; r1 += wv.y * hv.y;
            r2 += wv.z * hv.z; r3 += wv.w * hv.w;
          }
        }
        __syncthreads();
      }
      s_red[w][lane] = (r0 + r1) + (r2 + r3);
    }
    __syncthreads();
    if (blk < S1B && tid < 64) {
      const int b = tid >> 1, j_l = tid & 1, j = blk * 2 + j_l;
      float sm = (s_red[0][tid] + s_red[1][tid]) + (s_red[2][tid] + s_red[3][tid]);
      float val = enc_projB[(b * 100 + t) * 640 + j] + sm;
      st_coh_f32(&jt_ring[(size_t)i * HRS + b * 640 + j], fmaxf(val, 0.f));
    }
    gbarrier(arrive, go, ++it);

    // ---- stage 4: logits = jt @ W_out + b_out; argmax + fixed-point sumexp --
    {
      const int b = tid >> 3, v_l = tid & 7;
      const int v = blk * 8 + v_l;  // 0..4095
      const int kq = v_l;           // blank-column k-octant (block NB-1)
      float a0 = 0.f, a1 = 0.f, a2 = 0.f, a3 = 0.f;
      float p0 = 0.f, p1 = 0.f, p2 = 0.f, p3 = 0.f;
      const int rb = tid >> 3, q = tid & 7;
#pragma unroll 1
      for (int tt = 0; tt < 2; ++tt) {
        const float* src = jt_ring + (size_t)i * HRS + rb * 640 + tt * 320;
        stage_tile(s_tile, src, rb, q);
        __syncthreads();
        const float* wk = Wout_k4 + ((size_t)tt * 80 * 4097 + v) * 4;
#pragma unroll 8
        for (int cc = 0; cc < 80; ++cc) {
          float4 jv = tile_read(s_tile, b, cc);
          float4 wv = *(const float4*)(wk + (size_t)cc * 4097 * 4);
          a0 += wv.x * jv.x; a1 += wv.y * jv.y;
          a2 += wv.z * jv.z; a3 += wv.w * jv.w;
        }
        if (blk == NB - 1 && (kq >> 2) == tt) {
          const float* wb4 = Wout_k4 + ((size_t)(kq * 20) * 4097 + 4096) * 4;
          const int c0 = kq * 20 - tt * 80;
#pragma unroll
          for (int cc = 0; cc < 20; ++cc) {
            float4 jv = tile_read(s_tile, b, c0 + cc);
            float4 wv = *(const float4*)(wb4 + (size_t)cc * 4097 * 4);
            p0 += wv.x * jv.x; p1 += wv.y * jv.y;
            p2 += wv.z * jv.z; p3 += wv.w * jv.w;
          }
        }
        __syncthreads();
      }
      float acc = ((a0 + a1) + (a2 + a3)) + b_out[v];
      unsigned long long key =
          ((unsigned long long)f2ord(acc) << 32) | (unsigned)(4096 - v);
      unsigned long long isum =
          (unsigned long long)(expf(acc) * 4294967296.0f + 0.5f);
#pragma unroll
      for (int d = 1; d < 8; d <<= 1) {
        unsigned long long ok = shfl_xor_u64(key, d);
        if (ok > key) key = ok;
        isum += shfl_xor_u64(isum, d);
      }
      if (v_l == 0) {
        atomicMax(&kslot[((size_t)i * 32 + b) * 8 + (blk & 7)], key);
        atomicAdd(&sslot[((size_t)i * 32 + b) * 8 + (blk & 7)], isum);
      }
      if (blk == NB - 1) {  // BLANK column v=4096, k split over 8 lanes
        float part = (p0 + p1) + (p2 + p3);
#pragma unroll
        for (int d = 1; d < 8; d <<= 1) part += __shfl_xor(part, d, 64);
        if (kq == 0) {
          float aB = part + b_out[4096];
          unsigned long long key2 = ((unsigned long long)f2ord(aB) << 32);
          unsigned long long is2 =
              (unsigned long long)(expf(aB) * 4294967296.0f + 0.5f);
          atomicMax(&kslot[((size_t)i * 32 + b) * 8 + 7], key2);
          atomicAdd(&sslot[((size_t)i * 32 + b) * 8 + 7], is2);
        }
      }
    }
    gbarrier(arrive, go, ++it);
  }
}

extern "C" void kernel_launch(void* const* d_in, const int* in_sizes, int n_in,
                              void* d_out, int out_size, void* d_ws, size_t ws_size,
                              hipStream_t stream) {
  (void)in_sizes; (void)n_in; (void)out_size; (void)ws_size;
  const float* enc    = (const float*)d_in[0];
  const int*   lens   = (const int*)d_in[1];
  const float* embed  = (const float*)d_in[2];
  const float* W_i    = (const float*)d_in[3];
  const float* W_h    = (const float*)d_in[4];
  const float* b_lstm = (const float*)d_in[5];
  const float* W_enc  = (const float*)d_in[6];
  const float* W_pred = (const float*)d_in[7];
  const float* b_joint= (const float*)d_in[8];
  const float* W_out  = (const float*)d_in[9];
  const float* b_out  = (const float*)d_in[10];
  float* out = (float*)d_out;

  char* ws = (char*)d_ws;
  size_t off = 0;
  auto carve = [&](size_t bytes) -> void* {
    void* p = ws + off;
    off += (bytes + 255) & ~(size_t)255;
    return p;
  };
  unsigned* arrive           = (unsigned*)carve((size_t)NB * 4 * 4);
  unsigned* go               = (unsigned*)carve((size_t)64 * 4 * 4);
  unsigned long long* kslot  = (unsigned long long*)carve((size_t)51200 * 8);
  unsigned long long* sslot  = (unsigned long long*)carve((size_t)51200 * 8);
  float* h_ring   = (float*)carve((size_t)201 * HRS * 4);
  float* jt_ring  = (float*)carve((size_t)200 * HRS * 4);
  float* Wpred_t  = (float*)carve((size_t)640 * 640 * 4);
  float* Wcat_t   = (float*)carve((size_t)2560 * 1280 * 4);
  float* Wout_k4  = (float*)carve((size_t)160 * 4097 * 16);
  float* enc_projB= (float*)carve((size_t)32 * 100 * 640 * 4);

  rnnt_prep<<<2048, 256, 0, stream>>>(
      enc, W_i, W_h, W_pred, W_out, W_enc, b_joint,
      out, Wcat_t, Wpred_t, Wout_k4, enc_projB, h_ring, kslot, sslot, arrive, go);
  rnnt_decode<<<NB, 256, 0, stream>>>(
      lens, embed, b_lstm, b_out, out,
      Wcat_t, Wpred_t, Wout_k4, enc_projB, h_ring, jt_ring, kslot, sslot,
      arrive, go);
}

// Round 6
// 15659.705 us; speedup vs baseline: 3.1883x; 1.0026x over previous
//
#include <hip/hip_runtime.h>

// RNNT greedy decode. B=32, T=100, E=512, H=640, 4H=2560, J=640, V=4096 (BLANK).
// Batch-shared persistent decode (weights read once per iteration), 512 blocks.
// v6: (a) revert the 64KB-stride Wout_k4 layout (L1/L2 set aliasing made Wout
// uncacheable -> 15MB/iter HBM refetch); (b) per-block Wout slice (9 cols incl
// blank) held in LDS for all 200 iters; (c) 32x160 staging tile (same swizzle,
// same ascending-k accumulation order -> bit-identical numerics to r4/r5);
// (d) barrier master polls 2 flags per thread under a single vmcnt(0).

#define NB 512
#define S1B 320            // blocks doing LSTM + joint (2 j-columns each)
#define HRS 20480          // 32*640 floats per ring slot

__device__ __forceinline__ unsigned f2ord(float f) {
  unsigned u = __float_as_uint(f);
  return (u & 0x80000000u) ? ~u : (u | 0x80000000u);
}
__device__ __forceinline__ float ord2f(unsigned u) {
  return __uint_as_float((u & 0x80000000u) ? (u & 0x7fffffffu) : ~u);
}
__device__ __forceinline__ unsigned long long shfl_xor_u64(unsigned long long x, int m) {
  int lo = __shfl_xor((int)(unsigned)x, m, 64);
  int hi = __shfl_xor((int)(unsigned)(x >> 32), m, 64);
  return ((unsigned long long)(unsigned)hi << 32) | (unsigned)lo;
}

// ---- coherence-point accesses (flags + cross-block produced data) ----------
__device__ __forceinline__ void st_coh_f32(float* p, float v) {
  asm volatile("global_store_dword %0, %1, off sc0 sc1" :: "v"(p), "v"(v) : "memory");
}
__device__ __forceinline__ void st_coh_u32(unsigned* p, unsigned v) {
  asm volatile("global_store_dword %0, %1, off sc0 sc1" :: "v"(p), "v"(v) : "memory");
}
__device__ __forceinline__ unsigned ld_coh_u32(const unsigned* p) {
  unsigned r;
  asm volatile("global_load_dword %0, %1, off sc0 sc1\n\ts_waitcnt vmcnt(0)"
               : "=v"(r) : "v"(p) : "memory");
  return r;
}
__device__ __forceinline__ bool poll2(const unsigned* p1, const unsigned* p2,
                                      unsigned it) {
  unsigned r1, r2;
  asm volatile("global_load_dword %0, %2, off sc0 sc1\n\t"
               "global_load_dword %1, %3, off sc0 sc1\n\t"
               "s_waitcnt vmcnt(0)"
               : "=v"(r1), "=v"(r2) : "v"(p1), "v"(p2) : "memory");
  return (r1 >= it) && (r2 >= it);
}

// ---- global barrier: coherent flags, master (block 0) fan-out --------------
__device__ __forceinline__ void gbarrier(unsigned* __restrict__ arrive,
                                         unsigned* __restrict__ go, unsigned it) {
  const int blk = blockIdx.x, tid = threadIdx.x;
  __syncthreads();  // drains vmcnt per wave -> stores/atomics complete
  if (blk == 0) {
    int f1 = 1 + tid; if (f1 > 511) f1 = 511;
    int f2 = 257 + tid; if (f2 > 511) f2 = 511;
    while (!poll2(arrive + f1 * 4, arrive + f2 * 4, it))
      __builtin_amdgcn_s_sleep(1);
    __syncthreads();
    if (tid < 64) st_coh_u32(go + tid * 4, it);
    __syncthreads();
  } else {
    if (tid == 0) {
      st_coh_u32(arrive + blk * 4, it);
      while (ld_coh_u32(go + (blk & 63) * 4) < it) __builtin_amdgcn_s_sleep(1);
    }
    __syncthreads();
  }
}

// ---- LDS tile: 32 rows x 160 floats, XOR-swizzled 16B chunks ---------------
__device__ __forceinline__ void stage_tile(float (*__restrict__ t)[160],
                                           const float* __restrict__ src_row,
                                           int rb, int q) {
#pragma unroll
  for (int p = 0; p < 5; ++p) {
    int c = q + (p << 3);
    float4 v = *(const float4*)(src_row + (c << 2));
    *(float4*)&t[rb][(c ^ (rb & 7)) << 2] = v;
  }
}
__device__ __forceinline__ float4 tile_read(const float (*__restrict__ t)[160],
                                            int b, int c) {
  return *(const float4*)&t[b][(c ^ (b & 7)) << 2];
}

// ----------------- prep: init + weight transposes + enc projection ----------
__global__ __launch_bounds__(256) void rnnt_prep(
    const float* __restrict__ enc, const float* __restrict__ W_i,
    const float* __restrict__ W_h, const float* __restrict__ W_pred,
    const float* __restrict__ W_out, const float* __restrict__ W_enc,
    const float* __restrict__ b_joint,
    float* __restrict__ out, float* __restrict__ Wcat_t,
    float* __restrict__ Wpred_t, float* __restrict__ Wout_t,
    float* __restrict__ enc_projB, float* __restrict__ h_ring,
    unsigned long long* __restrict__ kslot, unsigned long long* __restrict__ sslot,
    unsigned* __restrict__ arrive, unsigned* __restrict__ go) {
  const int blk = blockIdx.x, tid = threadIdx.x;
  const int gtid = blk * 256 + tid;
  const int GT = gridDim.x * 256;
  __shared__ float s_tr[32][33];

  for (int x = gtid; x < 6464; x += GT) out[x] = (x < 6400) ? 4096.0f : 0.0f;
  for (int x = gtid; x < HRS; x += GT) h_ring[(size_t)200 * HRS + x] = 0.f;
  for (int x = gtid; x < 51200; x += GT) { kslot[x] = 0ull; sslot[x] = 0ull; }
  for (int x = gtid; x < NB * 4; x += GT) arrive[x] = 0u;
  for (int x = gtid; x < 64 * 4; x += GT) go[x] = 0u;

  {
    const int NT0 = 1600, NT1 = 1600, NT2 = 400, NT3 = 2580;  // 32x32 tiles
    for (int tl = blk; tl < NT0 + NT1 + NT2 + NT3; tl += gridDim.x) {
      const float* src; float* dst; int C, DS, DO, CT; int tt = tl;
      if (tt < NT0)               { src = W_i;    dst = Wcat_t;  C = 2560; DS = 1280; DO = 0;   CT = 80; }
      else if ((tt -= NT0) < NT1) { src = W_h;    dst = Wcat_t;  C = 2560; DS = 1280; DO = 640; CT = 80; }
      else if ((tt -= NT1) < NT2) { src = W_pred; dst = Wpred_t; C = 640;  DS = 640;  DO = 0;   CT = 20; }
      else { tt -= NT2;             src = W_out;  dst = Wout_t;  C = 4097; DS = 640;  DO = 0;   CT = 129; }
      int rt = tt / CT, ct = tt % CT;
      int r0 = rt * 32, c0 = ct * 32;
      __syncthreads();
#pragma unroll
      for (int p = 0; p < 4; ++p) {
        int rr = (tid >> 5) + 8 * p, cc = tid & 31;
        float v = 0.f;
        if (c0 + cc < C) v = src[(r0 + rr) * C + c0 + cc];
        s_tr[rr][cc] = v;
      }
      __syncthreads();
#pragma unroll
      for (int p = 0; p < 4; ++p) {
        int cc2 = (tid >> 5) + 8 * p, rr2 = tid & 31;
        if (c0 + cc2 < C) dst[(c0 + cc2) * DS + DO + r0 + rr2] = s_tr[rr2][cc2];
      }
    }
  }

  // enc_projB[b][t][j] = sum_e enc[b][e][t] * W_enc[e][j] + b_joint[j]
  for (int idx = gtid; idx < 2048000; idx += GT) {
    int b = idx / 64000, r = idx % 64000;
    int tt = r / 640, j = r % 640;
    const float* ep = enc + b * 51200;
    float acc = b_joint[j];
#pragma unroll 4
    for (int e = 0; e < 512; ++e) acc += ep[e * 100 + tt] * W_enc[e * 640 + j];
    enc_projB[idx] = acc;
  }
}

// ----------------- decode: persistent, batch-shared, 512 blocks -------------
__global__ __launch_bounds__(256, 2) void rnnt_decode(
    const int* __restrict__ lens, const float* __restrict__ embed,
    const float* __restrict__ b_lstm, const float* __restrict__ b_out,
    float* __restrict__ out,
    const float* __restrict__ Wcat_t, const float* __restrict__ Wpred_t,
    const float* __restrict__ Wout_t, const float* __restrict__ enc_projB,
    float* __restrict__ h_ring, float* __restrict__ jt_ring,
    unsigned long long* __restrict__ kslot, unsigned long long* __restrict__ sslot,
    unsigned* __restrict__ arrive, unsigned* __restrict__ go) {
  const int blk = blockIdx.x, tid = threadIdx.x;

  __shared__ float s_tile[32][160];     // 20KB staging tile (swizzled)
  __shared__ float s_wout[9 * 640];     // 22.5KB: this block's 8 cols + blank
  __shared__ float s_zp[2][4][32][2];
  __shared__ float s_red[4][64];
  __shared__ unsigned long long s_dk[32], s_ds[32];
  __shared__ int s_last[32], s_hsrc[32], s_commit[32];

  // one-time: copy this block's W_out columns into LDS (resident all 200 iters)
  for (int x = tid; x < 9 * 160; x += 256) {
    int col = x / 160, cc = x - col * 160;
    int vcol = (col < 8) ? blk * 8 + col : 4096;
    *(float4*)&s_wout[col * 640 + cc * 4] =
        *(const float4*)(Wout_t + (size_t)vcol * 640 + cc * 4);
  }

  // per-lane decoder state (lanes 0..31 track batch=lane, in EVERY block)
  int last_r = 4096, hsrc_r = 200, cnt_r = 0;
  bool blank_r = false;
  float score_r = 0.f;
  // per-thread LSTM cell state (tid<64 of S1 blocks: b=tid>>1, j=blk*2+(tid&1))
  float c_comm = 0.f, c_cand = 0.f;
  unsigned it = 0;
  const int len_b = lens[tid & 31];

  for (int i = 0;; ++i) {
    // ---- combine argmax/sumexp slots of iter i-1 (plain cached loads) ----
    if (i > 0) {
      int ip = i - 1;
      int b8 = tid >> 3, sl = tid & 7;
      unsigned long long kv = kslot[((size_t)ip * 32 + b8) * 8 + sl];
      unsigned long long sv = sslot[((size_t)ip * 32 + b8) * 8 + sl];
#pragma unroll
      for (int d = 1; d < 8; d <<= 1) {
        unsigned long long ok = shfl_xor_u64(kv, d);
        if (ok > kv) kv = ok;
        sv += shfl_xor_u64(sv, d);
      }
      if (sl == 0) { s_dk[b8] = kv; s_ds[b8] = sv; }
    }
    __syncthreads();
    if (tid < 32) {
      int b = tid;
      int cm = 0;
      if (i > 0) {
        unsigned long long key = s_dk[b], sum = s_ds[b];
        int kArg = 4096 - (int)(key & 0xffffffffu);
        float bl = ord2f((unsigned)(key >> 32));
        float lse = logf((float)sum * 0x1p-32f);
        float vsc = bl - lse;
        int im1 = i - 1, tp = im1 >> 1, sp = im1 & 1;
        bool blank_in = (sp == 0) ? (tp >= len_b) : blank_r;
        bool nb = blank_in || (kArg == 4096);
        blank_r = nb;
        if (!nb) {
          if (blk == b) out[b * 200 + cnt_r] = (float)kArg;
          last_r = kArg; hsrc_r = im1; cnt_r++; score_r += vsc; cm = 1;
        }
      }
      if (i == 200 && blk == b) { out[6400 + b] = (float)cnt_r; out[6432 + b] = score_r; }
      s_last[b] = last_r; s_hsrc[b] = hsrc_r; s_commit[b] = cm;
    }
    __syncthreads();
    if (i == 200) return;
    const int t = i >> 1;

    // ---- stage 1: LSTM z = [x;h]@[W_i;W_h]+b via 8 LDS tile phases ----
    if (blk < S1B) {
      const int b = tid & 31;
      const int g = (tid >> 5) & 3;
      const int half = tid >> 7;
      const int j0 = blk * 2;
      float a0 = 0.f, a1 = 0.f, a2 = 0.f, a3 = 0.f;
      float e0 = 0.f, e1 = 0.f, e2 = 0.f, e3 = 0.f;
      if (i > 0) {
        const int rb = tid >> 3, q = tid & 7;
#pragma unroll 1
        for (int tt = 0; tt < 8; ++tt) {  // tiles 0-3 = x; 4-7 = h_prev
          const float* src = (tt < 4)
              ? embed + (size_t)s_last[rb] * 640 + tt * 160
              : h_ring + (size_t)s_hsrc[rb] * HRS + rb * 640 + (tt - 4) * 160;
          stage_tile(s_tile, src, rb, q);
          __syncthreads();
          if ((tt >> 2) == half) {
            const float* wr = Wcat_t + (size_t)(g * 640 + j0) * 1280 +
                              half * 640 + (tt & 3) * 160;
            const float* wr2 = wr + 1280;
#pragma unroll 8
            for (int cc = 0; cc < 40; ++cc) {
              float4 xv = tile_read(s_tile, b, cc);
              float4 wa = *(const float4*)(wr + cc * 4);
              float4 wb = *(const float4*)(wr2 + cc * 4);
              a0 += wa.x * xv.x; a1 += wa.y * xv.y;
              a2 += wa.z * xv.z; a3 += wa.w * xv.w;
              e0 += wb.x * xv.x; e1 += wb.y * xv.y;
              e2 += wb.z * xv.z; e3 += wb.w * xv.w;
            }
          }
          __syncthreads();
        }
      }
      float z0 = (a0 + a1) + (a2 + a3);
      float z1 = (e0 + e1) + (e2 + e3);
      if (half == 0) { z0 += b_lstm[g * 640 + j0]; z1 += b_lstm[g * 640 + j0 + 1]; }
      s_zp[half][g][b][0] = z0;
      s_zp[half][g][b][1] = z1;
    }
    __syncthreads();
    if (blk < S1B && tid < 64) {
      const int b = tid >> 1, j_l = tid & 1;
      float zi = s_zp[0][0][b][j_l] + s_zp[1][0][b][j_l];
      float zf = s_zp[0][1][b][j_l] + s_zp[1][1][b][j_l];
      float zg = s_zp[0][2][b][j_l] + s_zp[1][2][b][j_l];
      float zo = s_zp[0][3][b][j_l] + s_zp[1][3][b][j_l];
      if (s_commit[b]) c_comm = c_cand;  // advance committed cell state
      float ig = 1.f / (1.f + expf(-zi));
      float fg = 1.f / (1.f + expf(-zf));
      float og = 1.f / (1.f + expf(-zo));
      float cn = fg * c_comm + ig * tanhf(zg);
      float hn = og * tanhf(cn);
      c_cand = cn;
      st_coh_f32(&h_ring[(size_t)i * HRS + b * 640 + blk * 2 + j_l], hn);
    }
    gbarrier(arrive, go, ++it);

    // ---- stage 3: jt = relu(enc_projB[:,t] + h1 @ W_pred) via LDS tiles ----
    if (blk < S1B) {
      const int w = tid >> 6, lane = tid & 63, bb = lane >> 1, j_l = lane & 1;
      const int j = blk * 2 + j_l;
      const int rb = tid >> 3, q = tid & 7;
      float r0 = 0.f, r1 = 0.f, r2 = 0.f, r3 = 0.f;
#pragma unroll 1
      for (int tt = 0; tt < 4; ++tt) {
        const float* src = h_ring + (size_t)i * HRS + rb * 640 + tt * 160;
        stage_tile(s_tile, src, rb, q);
        __syncthreads();
        if (w == tt) {
          const float* wp = Wpred_t + (size_t)j * 640 + w * 160;
#pragma unroll 8
          for (int cc = 0; cc < 40; ++cc) {
            float4 hv = tile_read(s_tile, bb, cc);
            float4 wv = *(const float4*)(wp + cc * 4);
            r0 += wv.x * hv.x; r1 += wv.y * hv.y;
            r2 += wv.z * hv.z; r3 += wv.w * hv.w;
          }
        }
        __syncthreads();
      }
      s_red[w][lane] = (r0 + r1) + (r2 + r3);
    }
    __syncthreads();
    if (blk < S1B && tid < 64) {
      const int b = tid >> 1, j_l = tid & 1, j = blk * 2 + j_l;
      float sm = (s_red[0][tid] + s_red[1][tid]) + (s_red[2][tid] + s_red[3][tid]);
      float val = enc_projB[(b * 100 + t) * 640 + j] + sm;
      st_coh_f32(&jt_ring[(size_t)i * HRS + b * 640 + j], fmaxf(val, 0.f));
    }
    gbarrier(arrive, go, ++it);

    // ---- stage 4: logits = jt @ W_out + b_out (weights in LDS) ----
    {
      const int b = tid >> 3, v_l = tid & 7;
      const int v = blk * 8 + v_l;  // 0..4095
      const int kq = v_l;           // blank-column k-octant (block NB-1)
      float a0 = 0.f, a1 = 0.f, a2 = 0.f, a3 = 0.f;
      float p0 = 0.f, p1 = 0.f, p2 = 0.f, p3 = 0.f;
      const int rb = tid >> 3, q = tid & 7;
#pragma unroll 1
      for (int tt = 0; tt < 4; ++tt) {
        const float* src = jt_ring + (size_t)i * HRS + rb * 640 + tt * 160;
        stage_tile(s_tile, src, rb, q);
        __syncthreads();
        const float* wk = s_wout + v_l * 640 + tt * 160;
#pragma unroll 8
        for (int cc = 0; cc < 40; ++cc) {
          float4 jv = tile_read(s_tile, b, cc);
          float4 wv = *(const float4*)(wk + cc * 4);
          a0 += wv.x * jv.x; a1 += wv.y * jv.y;
          a2 += wv.z * jv.z; a3 += wv.w * jv.w;
        }
        if (blk == NB - 1 && (kq >> 1) == tt) {
          const float* wb4 = s_wout + 8 * 640 + kq * 80;
          const int c0 = (kq & 1) * 20;
#pragma unroll
          for (int cc = 0; cc < 20; ++cc) {
            float4 jv = tile_read(s_tile, b, c0 + cc);
            float4 wv = *(const float4*)(wb4 + cc * 4);
            p0 += wv.x * jv.x; p1 += wv.y * jv.y;
            p2 += wv.z * jv.z; p3 += wv.w * jv.w;
          }
        }
        __syncthreads();
      }
      float acc = ((a0 + a1) + (a2 + a3)) + b_out[v];
      unsigned long long key =
          ((unsigned long long)f2ord(acc) << 32) | (unsigned)(4096 - v);
      unsigned long long isum =
          (unsigned long long)(expf(acc) * 4294967296.0f + 0.5f);
#pragma unroll
      for (int d = 1; d < 8; d <<= 1) {
        unsigned long long ok = shfl_xor_u64(key, d);
        if (ok > key) key = ok;
        isum += shfl_xor_u64(isum, d);
      }
      if (v_l == 0) {
        atomicMax(&kslot[((size_t)i * 32 + b) * 8 + (blk & 7)], key);
        atomicAdd(&sslot[((size_t)i * 32 + b) * 8 + (blk & 7)], isum);
      }
      if (blk == NB - 1) {  // BLANK column v=4096, k split over 8 lanes
        float part = (p0 + p1) + (p2 + p3);
#pragma unroll
        for (int d = 1; d < 8; d <<= 1) part += __shfl_xor(part, d, 64);
        if (kq == 0) {
          float aB = part + b_out[4096];
          unsigned long long key2 = ((unsigned long long)f2ord(aB) << 32);
          unsigned long long is2 =
              (unsigned long long)(expf(aB) * 4294967296.0f + 0.5f);
          atomicMax(&kslot[((size_t)i * 32 + b) * 8 + 7], key2);
          atomicAdd(&sslot[((size_t)i * 32 + b) * 8 + 7], is2);
        }
      }
    }
    gbarrier(arrive, go, ++it);
  }
}

extern "C" void kernel_launch(void* const* d_in, const int* in_sizes, int n_in,
                              void* d_out, int out_size, void* d_ws, size_t ws_size,
                              hipStream_t stream) {
  (void)in_sizes; (void)n_in; (void)out_size; (void)ws_size;
  const float* enc    = (const float*)d_in[0];
  const int*   lens   = (const int*)d_in[1];
  const float* embed  = (const float*)d_in[2];
  const float* W_i    = (const float*)d_in[3];
  const float* W_h    = (const float*)d_in[4];
  const float* b_lstm = (const float*)d_in[5];
  const float* W_enc  = (const float*)d_in[6];
  const float* W_pred = (const float*)d_in[7];
  const float* b_joint= (const float*)d_in[8];
  const float* W_out  = (const float*)d_in[9];
  const float* b_out  = (const float*)d_in[10];
  float* out = (float*)d_out;

  char* ws = (char*)d_ws;
  size_t off = 0;
  auto carve = [&](size_t bytes) -> void* {
    void* p = ws + off;
    off += (bytes + 255) & ~(size_t)255;
    return p;
  };
  unsigned* arrive           = (unsigned*)carve((size_t)NB * 4 * 4);
  unsigned* go               = (unsigned*)carve((size_t)64 * 4 * 4);
  unsigned long long* kslot  = (unsigned long long*)carve((size_t)51200 * 8);
  unsigned long long* sslot  = (unsigned long long*)carve((size_t)51200 * 8);
  float* h_ring   = (float*)carve((size_t)201 * HRS * 4);
  float* jt_ring  = (float*)carve((size_t)200 * HRS * 4);
  float* Wpred_t  = (float*)carve((size_t)640 * 640 * 4);
  float* Wcat_t   = (float*)carve((size_t)2560 * 1280 * 4);
  float* Wout_t   = (float*)carve((size_t)4097 * 640 * 4);
  float* enc_projB= (float*)carve((size_t)32 * 100 * 640 * 4);

  rnnt_prep<<<2048, 256, 0, stream>>>(
      enc, W_i, W_h, W_pred, W_out, W_enc, b_joint,
      out, Wcat_t, Wpred_t, Wout_t, enc_projB, h_ring, kslot, sslot, arrive, go);
  rnnt_decode<<<NB, 256, 0, stream>>>(
      lens, embed, b_lstm, b_out, out,
      Wcat_t, Wpred_t, Wout_t, enc_projB, h_ring, jt_ring, kslot, sslot,
      arrive, go);
}

// Round 7
// 12763.768 us; speedup vs baseline: 3.9117x; 1.2269x over previous
//
#include <hip/hip_runtime.h>

// RNNT greedy decode. B=32, T=100, E=512, H=640, 4H=2560, J=640, V=4096 (BLANK).
// Batch-shared persistent decode (weights read once per iteration), 512 blocks.
// v7: (a) barrier flags spread across fabric channels (arrive stride 256B, go
// stride 1KB) + worker poll backoff -> kill coherent-poll congestion;
// (b) double-buffered tile staging (prefetch next chunk to regs, overlap with
// compute) -> hide fabric RTT off the critical path; (c) s_wout column stride
// padded 640->644 floats (bank-group v_l*4, conflict-free); blank column reads
// L2-cached global (block 511 only). Compute accumulation order unchanged from
// r4/r5/r6 (absmax 0.0).

#define NB 512
#define S1B 320            // blocks doing LSTM + joint (2 j-columns each)
#define HRS 20480          // 32*640 floats per ring slot
#define ARRS 64            // arrive flag stride (words) = 256B
#define GOS 256            // go flag stride (words) = 1KB

__device__ __forceinline__ unsigned f2ord(float f) {
  unsigned u = __float_as_uint(f);
  return (u & 0x80000000u) ? ~u : (u | 0x80000000u);
}
__device__ __forceinline__ float ord2f(unsigned u) {
  return __uint_as_float((u & 0x80000000u) ? (u & 0x7fffffffu) : ~u);
}
__device__ __forceinline__ unsigned long long shfl_xor_u64(unsigned long long x, int m) {
  int lo = __shfl_xor((int)(unsigned)x, m, 64);
  int hi = __shfl_xor((int)(unsigned)(x >> 32), m, 64);
  return ((unsigned long long)(unsigned)hi << 32) | (unsigned)lo;
}

// ---- coherence-point accesses (flags + cross-block produced data) ----------
__device__ __forceinline__ void st_coh_f32(float* p, float v) {
  asm volatile("global_store_dword %0, %1, off sc0 sc1" :: "v"(p), "v"(v) : "memory");
}
__device__ __forceinline__ void st_coh_u32(unsigned* p, unsigned v) {
  asm volatile("global_store_dword %0, %1, off sc0 sc1" :: "v"(p), "v"(v) : "memory");
}
__device__ __forceinline__ unsigned ld_coh_u32(const unsigned* p) {
  unsigned r;
  asm volatile("global_load_dword %0, %1, off sc0 sc1\n\ts_waitcnt vmcnt(0)"
               : "=v"(r) : "v"(p) : "memory");
  return r;
}
__device__ __forceinline__ bool poll2(const unsigned* p1, const unsigned* p2,
                                      unsigned it) {
  unsigned r1, r2;
  asm volatile("global_load_dword %0, %2, off sc0 sc1\n\t"
               "global_load_dword %1, %3, off sc0 sc1\n\t"
               "s_waitcnt vmcnt(0)"
               : "=v"(r1), "=v"(r2) : "v"(p1), "v"(p2) : "memory");
  return (r1 >= it) && (r2 >= it);
}

// ---- global barrier: spread coherent flags, master (block 0) fan-out -------
__device__ __forceinline__ void gbarrier(unsigned* __restrict__ arrive,
                                         unsigned* __restrict__ go, unsigned it) {
  const int blk = blockIdx.x, tid = threadIdx.x;
  __syncthreads();  // drains vmcnt per wave -> stores/atomics complete
  if (blk == 0) {
    int f1 = 1 + tid; if (f1 > 511) f1 = 511;
    int f2 = 257 + tid; if (f2 > 511) f2 = 511;
    while (!poll2(arrive + f1 * ARRS, arrive + f2 * ARRS, it))
      __builtin_amdgcn_s_sleep(1);
    __syncthreads();
    if (tid < 64) st_coh_u32(go + tid * GOS, it);
    __syncthreads();
  } else {
    if (tid == 0) {
      st_coh_u32(arrive + blk * ARRS, it);
      while (ld_coh_u32(go + (blk & 63) * GOS) < it) __builtin_amdgcn_s_sleep(4);
    }
    __syncthreads();
  }
}

// ---- LDS tile: 32 rows x 160 floats, XOR-swizzled 16B chunks ---------------
__device__ __forceinline__ float4 tile_read(const float (*__restrict__ t)[160],
                                            int b, int c) {
  return *(const float4*)&t[b][(c ^ (b & 7)) << 2];
}

// ----------------- prep: init + weight transposes + enc projection ----------
__global__ __launch_bounds__(256) void rnnt_prep(
    const float* __restrict__ enc, const float* __restrict__ W_i,
    const float* __restrict__ W_h, const float* __restrict__ W_pred,
    const float* __restrict__ W_out, const float* __restrict__ W_enc,
    const float* __restrict__ b_joint,
    float* __restrict__ out, float* __restrict__ Wcat_t,
    float* __restrict__ Wpred_t, float* __restrict__ Wout_t,
    float* __restrict__ enc_projB, float* __restrict__ h_ring,
    unsigned long long* __restrict__ kslot, unsigned long long* __restrict__ sslot,
    unsigned* __restrict__ arrive, unsigned* __restrict__ go) {
  const int blk = blockIdx.x, tid = threadIdx.x;
  const int gtid = blk * 256 + tid;
  const int GT = gridDim.x * 256;
  __shared__ float s_tr[32][33];

  for (int x = gtid; x < 6464; x += GT) out[x] = (x < 6400) ? 4096.0f : 0.0f;
  for (int x = gtid; x < HRS; x += GT) h_ring[(size_t)200 * HRS + x] = 0.f;
  for (int x = gtid; x < 51200; x += GT) { kslot[x] = 0ull; sslot[x] = 0ull; }
  for (int x = gtid; x < NB * ARRS; x += GT) arrive[x] = 0u;
  for (int x = gtid; x < 64 * GOS; x += GT) go[x] = 0u;

  {
    const int NT0 = 1600, NT1 = 1600, NT2 = 400, NT3 = 2580;  // 32x32 tiles
    for (int tl = blk; tl < NT0 + NT1 + NT2 + NT3; tl += gridDim.x) {
      const float* src; float* dst; int C, DS, DO, CT; int tt = tl;
      if (tt < NT0)               { src = W_i;    dst = Wcat_t;  C = 2560; DS = 1280; DO = 0;   CT = 80; }
      else if ((tt -= NT0) < NT1) { src = W_h;    dst = Wcat_t;  C = 2560; DS = 1280; DO = 640; CT = 80; }
      else if ((tt -= NT1) < NT2) { src = W_pred; dst = Wpred_t; C = 640;  DS = 640;  DO = 0;   CT = 20; }
      else { tt -= NT2;             src = W_out;  dst = Wout_t;  C = 4097; DS = 640;  DO = 0;   CT = 129; }
      int rt = tt / CT, ct = tt % CT;
      int r0 = rt * 32, c0 = ct * 32;
      __syncthreads();
#pragma unroll
      for (int p = 0; p < 4; ++p) {
        int rr = (tid >> 5) + 8 * p, cc = tid & 31;
        float v = 0.f;
        if (c0 + cc < C) v = src[(r0 + rr) * C + c0 + cc];
        s_tr[rr][cc] = v;
      }
      __syncthreads();
#pragma unroll
      for (int p = 0; p < 4; ++p) {
        int cc2 = (tid >> 5) + 8 * p, rr2 = tid & 31;
        if (c0 + cc2 < C) dst[(c0 + cc2) * DS + DO + r0 + rr2] = s_tr[rr2][cc2];
      }
    }
  }

  // enc_projB[b][t][j] = sum_e enc[b][e][t] * W_enc[e][j] + b_joint[j]
  for (int idx = gtid; idx < 2048000; idx += GT) {
    int b = idx / 64000, r = idx % 64000;
    int tt = r / 640, j = r % 640;
    const float* ep = enc + b * 51200;
    float acc = b_joint[j];
#pragma unroll 4
    for (int e = 0; e < 512; ++e) acc += ep[e * 100 + tt] * W_enc[e * 640 + j];
    enc_projB[idx] = acc;
  }
}

// ----------------- decode: persistent, batch-shared, 512 blocks -------------
__global__ __launch_bounds__(256, 2) void rnnt_decode(
    const int* __restrict__ lens, const float* __restrict__ embed,
    const float* __restrict__ b_lstm, const float* __restrict__ b_out,
    float* __restrict__ out,
    const float* __restrict__ Wcat_t, const float* __restrict__ Wpred_t,
    const float* __restrict__ Wout_t, const float* __restrict__ enc_projB,
    float* __restrict__ h_ring, float* __restrict__ jt_ring,
    unsigned long long* __restrict__ kslot, unsigned long long* __restrict__ sslot,
    unsigned* __restrict__ arrive, unsigned* __restrict__ go) {
  const int blk = blockIdx.x, tid = threadIdx.x;

  __shared__ float s_tile[32][160];     // 20KB staging tile (swizzled)
  __shared__ float s_wout[8 * 644];     // 20.6KB, stride 644 (bank-spread)
  __shared__ float s_zp[2][4][32][2];
  __shared__ float s_red[4][64];
  __shared__ unsigned long long s_dk[32], s_ds[32];
  __shared__ int s_last[32], s_hsrc[32], s_commit[32];

  // one-time: copy this block's 8 W_out columns into LDS (padded stride)
  for (int x = tid; x < 8 * 160; x += 256) {
    int col = x / 160, cc = x - col * 160;
    *(float4*)&s_wout[col * 644 + cc * 4] =
        *(const float4*)(Wout_t + (size_t)(blk * 8 + col) * 640 + cc * 4);
  }

  // per-lane decoder state (lanes 0..31 track batch=lane, in EVERY block)
  int last_r = 4096, hsrc_r = 200, cnt_r = 0;
  bool blank_r = false;
  float score_r = 0.f;
  // per-thread LSTM cell state (tid<64 of S1 blocks: b=tid>>1, j=blk*2+(tid&1))
  float c_comm = 0.f, c_cand = 0.f;
  unsigned it = 0;
  const int len_b = lens[tid & 31];
  const int rb = tid >> 3, q = tid & 7;  // staging role (all stages)

  for (int i = 0;; ++i) {
    // ---- combine argmax/sumexp slots of iter i-1 (plain cached loads) ----
    if (i > 0) {
      int ip = i - 1;
      int b8 = tid >> 3, sl = tid & 7;
      unsigned long long kv = kslot[((size_t)ip * 32 + b8) * 8 + sl];
      unsigned long long sv = sslot[((size_t)ip * 32 + b8) * 8 + sl];
#pragma unroll
      for (int d = 1; d < 8; d <<= 1) {
        unsigned long long ok = shfl_xor_u64(kv, d);
        if (ok > kv) kv = ok;
        sv += shfl_xor_u64(sv, d);
      }
      if (sl == 0) { s_dk[b8] = kv; s_ds[b8] = sv; }
    }
    __syncthreads();
    if (tid < 32) {
      int b = tid;
      int cm = 0;
      if (i > 0) {
        unsigned long long key = s_dk[b], sum = s_ds[b];
        int kArg = 4096 - (int)(key & 0xffffffffu);
        float bl = ord2f((unsigned)(key >> 32));
        float lse = logf((float)sum * 0x1p-32f);
        float vsc = bl - lse;
        int im1 = i - 1, tp = im1 >> 1, sp = im1 & 1;
        bool blank_in = (sp == 0) ? (tp >= len_b) : blank_r;
        bool nb = blank_in || (kArg == 4096);
        blank_r = nb;
        if (!nb) {
          if (blk == b) out[b * 200 + cnt_r] = (float)kArg;
          last_r = kArg; hsrc_r = im1; cnt_r++; score_r += vsc; cm = 1;
        }
      }
      if (i == 200 && blk == b) { out[6400 + b] = (float)cnt_r; out[6432 + b] = score_r; }
      s_last[b] = last_r; s_hsrc[b] = hsrc_r; s_commit[b] = cm;
    }
    __syncthreads();
    if (i == 200) return;
    const int t = i >> 1;

    // ---- stage 1: LSTM z via 8 double-buffered LDS tile phases ----
    if (blk < S1B) {
      const int b = tid & 31;
      const int g = (tid >> 5) & 3;
      const int half = tid >> 7;
      const int j0 = blk * 2;
      float a0 = 0.f, a1 = 0.f, a2 = 0.f, a3 = 0.f;
      float e0 = 0.f, e1 = 0.f, e2 = 0.f, e3 = 0.f;
      if (i > 0) {
        float4 pf0, pf1, pf2, pf3, pf4;
        {
          const float* s0 = embed + (size_t)s_last[rb] * 640;
          pf0 = *(const float4*)(s0 + (q << 2));
          pf1 = *(const float4*)(s0 + ((q + 8) << 2));
          pf2 = *(const float4*)(s0 + ((q + 16) << 2));
          pf3 = *(const float4*)(s0 + ((q + 24) << 2));
          pf4 = *(const float4*)(s0 + ((q + 32) << 2));
        }
#pragma unroll 1
        for (int tt = 0; tt < 8; ++tt) {  // tiles 0-3 = x; 4-7 = h_prev
          *(float4*)&s_tile[rb][((q)      ^ (rb & 7)) << 2] = pf0;
          *(float4*)&s_tile[rb][((q + 8)  ^ (rb & 7)) << 2] = pf1;
          *(float4*)&s_tile[rb][((q + 16) ^ (rb & 7)) << 2] = pf2;
          *(float4*)&s_tile[rb][((q + 24) ^ (rb & 7)) << 2] = pf3;
          *(float4*)&s_tile[rb][((q + 32) ^ (rb & 7)) << 2] = pf4;
          if (tt < 7) {  // prefetch next tile (overlaps compute below)
            const float* src = (tt + 1 < 4)
                ? embed + (size_t)s_last[rb] * 640 + (tt + 1) * 160
                : h_ring + (size_t)s_hsrc[rb] * HRS + rb * 640 + (tt - 3) * 160;
            pf0 = *(const float4*)(src + (q << 2));
            pf1 = *(const float4*)(src + ((q + 8) << 2));
            pf2 = *(const float4*)(src + ((q + 16) << 2));
            pf3 = *(const float4*)(src + ((q + 24) << 2));
            pf4 = *(const float4*)(src + ((q + 32) << 2));
          }
          __syncthreads();
          if ((tt >> 2) == half) {
            const float* wr = Wcat_t + (size_t)(g * 640 + j0) * 1280 +
                              half * 640 + (tt & 3) * 160;
            const float* wr2 = wr + 1280;
#pragma unroll 8
            for (int cc = 0; cc < 40; ++cc) {
              float4 xv = tile_read(s_tile, b, cc);
              float4 wa = *(const float4*)(wr + cc * 4);
              float4 wb = *(const float4*)(wr2 + cc * 4);
              a0 += wa.x * xv.x; a1 += wa.y * xv.y;
              a2 += wa.z * xv.z; a3 += wa.w * xv.w;
              e0 += wb.x * xv.x; e1 += wb.y * xv.y;
              e2 += wb.z * xv.z; e3 += wb.w * xv.w;
            }
          }
          __syncthreads();
        }
      }
      float z0 = (a0 + a1) + (a2 + a3);
      float z1 = (e0 + e1) + (e2 + e3);
      if (half == 0) { z0 += b_lstm[g * 640 + j0]; z1 += b_lstm[g * 640 + j0 + 1]; }
      s_zp[half][g][b][0] = z0;
      s_zp[half][g][b][1] = z1;
    }
    __syncthreads();
    if (blk < S1B && tid < 64) {
      const int b = tid >> 1, j_l = tid & 1;
      float zi = s_zp[0][0][b][j_l] + s_zp[1][0][b][j_l];
      float zf = s_zp[0][1][b][j_l] + s_zp[1][1][b][j_l];
      float zg = s_zp[0][2][b][j_l] + s_zp[1][2][b][j_l];
      float zo = s_zp[0][3][b][j_l] + s_zp[1][3][b][j_l];
      if (s_commit[b]) c_comm = c_cand;  // advance committed cell state
      float ig = 1.f / (1.f + expf(-zi));
      float fg = 1.f / (1.f + expf(-zf));
      float og = 1.f / (1.f + expf(-zo));
      float cn = fg * c_comm + ig * tanhf(zg);
      float hn = og * tanhf(cn);
      c_cand = cn;
      st_coh_f32(&h_ring[(size_t)i * HRS + b * 640 + blk * 2 + j_l], hn);
    }
    gbarrier(arrive, go, ++it);

    // ---- stage 3: jt = relu(enc_projB[:,t] + h1 @ W_pred), dbuf tiles ----
    if (blk < S1B) {
      const int w = tid >> 6, lane = tid & 63, bb = lane >> 1, j_l = lane & 1;
      const int j = blk * 2 + j_l;
      float r0 = 0.f, r1 = 0.f, r2 = 0.f, r3 = 0.f;
      float4 pf0, pf1, pf2, pf3, pf4;
      {
        const float* s0 = h_ring + (size_t)i * HRS + rb * 640;
        pf0 = *(const float4*)(s0 + (q << 2));
        pf1 = *(const float4*)(s0 + ((q + 8) << 2));
        pf2 = *(const float4*)(s0 + ((q + 16) << 2));
        pf3 = *(const float4*)(s0 + ((q + 24) << 2));
        pf4 = *(const float4*)(s0 + ((q + 32) << 2));
      }
#pragma unroll 1
      for (int tt = 0; tt < 4; ++tt) {
        *(float4*)&s_tile[rb][((q)      ^ (rb & 7)) << 2] = pf0;
        *(float4*)&s_tile[rb][((q + 8)  ^ (rb & 7)) << 2] = pf1;
        *(float4*)&s_tile[rb][((q + 16) ^ (rb & 7)) << 2] = pf2;
        *(float4*)&s_tile[rb][((q + 24) ^ (rb & 7)) << 2] = pf3;
        *(float4*)&s_tile[rb][((q + 32) ^ (rb & 7)) << 2] = pf4;
        if (tt < 3) {
          const float* src = h_ring + (size_t)i * HRS + rb * 640 + (tt + 1) * 160;
          pf0 = *(const float4*)(src + (q << 2));
          pf1 = *(const float4*)(src + ((q + 8) << 2));
          pf2 = *(const float4*)(src + ((q + 16) << 2));
          pf3 = *(const float4*)(src + ((q + 24) << 2));
          pf4 = *(const float4*)(src + ((q + 32) << 2));
        }
        __syncthreads();
        if (w == tt) {
          const float* wp = Wpred_t + (size_t)j * 640 + w * 160;
#pragma unroll 8
          for (int cc = 0; cc < 40; ++cc) {
            float4 hv = tile_read(s_tile, bb, cc);
            float4 wv = *(const float4*)(wp + cc * 4);
            r0 += wv.x * hv.x; r1 += wv.y * hv.y;
            r2 += wv.z * hv.z; r3 += wv.w * hv.w;
          }
        }
        __syncthreads();
      }
      s_red[w][lane] = (r0 + r1) + (r2 + r3);
    }
    __syncthreads();
    if (blk < S1B && tid < 64) {
      const int b = tid >> 1, j_l = tid & 1, j = blk * 2 + j_l;
      float sm = (s_red[0][tid] + s_red[1][tid]) + (s_red[2][tid] + s_red[3][tid]);
      float val = enc_projB[(b * 100 + t) * 640 + j] + sm;
      st_coh_f32(&jt_ring[(size_t)i * HRS + b * 640 + j], fmaxf(val, 0.f));
    }
    gbarrier(arrive, go, ++it);

    // ---- stage 4: logits = jt @ W_out + b_out (weights in LDS), dbuf ----
    {
      const int b = tid >> 3, v_l = tid & 7;
      const int v = blk * 8 + v_l;  // 0..4095
      const int kq = v_l;           // blank-column k-octant (block NB-1)
      float a0 = 0.f, a1 = 0.f, a2 = 0.f, a3 = 0.f;
      float p0 = 0.f, p1 = 0.f, p2 = 0.f, p3 = 0.f;
      float4 pf0, pf1, pf2, pf3, pf4;
      {
        const float* s0 = jt_ring + (size_t)i * HRS + rb * 640;
        pf0 = *(const float4*)(s0 + (q << 2));
        pf1 = *(const float4*)(s0 + ((q + 8) << 2));
        pf2 = *(const float4*)(s0 + ((q + 16) << 2));
        pf3 = *(const float4*)(s0 + ((q + 24) << 2));
        pf4 = *(const float4*)(s0 + ((q + 32) << 2));
      }
#pragma unroll 1
      for (int tt = 0; tt < 4; ++tt) {
        *(float4*)&s_tile[rb][((q)      ^ (rb & 7)) << 2] = pf0;
        *(float4*)&s_tile[rb][((q + 8)  ^ (rb & 7)) << 2] = pf1;
        *(float4*)&s_tile[rb][((q + 16) ^ (rb & 7)) << 2] = pf2;
        *(float4*)&s_tile[rb][((q + 24) ^ (rb & 7)) << 2] = pf3;
        *(float4*)&s_tile[rb][((q + 32) ^ (rb & 7)) << 2] = pf4;
        if (tt < 3) {
          const float* src = jt_ring + (size_t)i * HRS + rb * 640 + (tt + 1) * 160;
          pf0 = *(const float4*)(src + (q << 2));
          pf1 = *(const float4*)(src + ((q + 8) << 2));
          pf2 = *(const float4*)(src + ((q + 16) << 2));
          pf3 = *(const float4*)(src + ((q + 24) << 2));
          pf4 = *(const float4*)(src + ((q + 32) << 2));
        }
        __syncthreads();
        const float* wk = s_wout + v_l * 644 + tt * 160;
#pragma unroll 8
        for (int cc = 0; cc < 40; ++cc) {
          float4 jv = tile_read(s_tile, b, cc);
          float4 wv = *(const float4*)(wk + cc * 4);
          a0 += wv.x * jv.x; a1 += wv.y * jv.y;
          a2 += wv.z * jv.z; a3 += wv.w * jv.w;
        }
        if (blk == NB - 1 && (kq >> 1) == tt) {
          const float* wb4 = Wout_t + (size_t)4096 * 640 + kq * 80;  // L2-cached
          const int c0 = (kq & 1) * 20;
#pragma unroll
          for (int cc = 0; cc < 20; ++cc) {
            float4 jv = tile_read(s_tile, b, c0 + cc);
            float4 wv = *(const float4*)(wb4 + cc * 4);
            p0 += wv.x * jv.x; p1 += wv.y * jv.y;
            p2 += wv.z * jv.z; p3 += wv.w * jv.w;
          }
        }
        __syncthreads();
      }
      float acc = ((a0 + a1) + (a2 + a3)) + b_out[v];
      unsigned long long key =
          ((unsigned long long)f2ord(acc) << 32) | (unsigned)(4096 - v);
      unsigned long long isum =
          (unsigned long long)(expf(acc) * 4294967296.0f + 0.5f);
#pragma unroll
      for (int d = 1; d < 8; d <<= 1) {
        unsigned long long ok = shfl_xor_u64(key, d);
        if (ok > key) key = ok;
        isum += shfl_xor_u64(isum, d);
      }
      if (v_l == 0) {
        atomicMax(&kslot[((size_t)i * 32 + b) * 8 + (blk & 7)], key);
        atomicAdd(&sslot[((size_t)i * 32 + b) * 8 + (blk & 7)], isum);
      }
      if (blk == NB - 1) {  // BLANK column v=4096, k split over 8 lanes
        float part = (p0 + p1) + (p2 + p3);
#pragma unroll
        for (int d = 1; d < 8; d <<= 1) part += __shfl_xor(part, d, 64);
        if (kq == 0) {
          float aB = part + b_out[4096];
          unsigned long long key2 = ((unsigned long long)f2ord(aB) << 32);
          unsigned long long is2 =
              (unsigned long long)(expf(aB) * 4294967296.0f + 0.5f);
          atomicMax(&kslot[((size_t)i * 32 + b) * 8 + 7], key2);
          atomicAdd(&sslot[((size_t)i * 32 + b) * 8 + 7], is2);
        }
      }
    }
    gbarrier(arrive, go, ++it);
  }
}

extern "C" void kernel_launch(void* const* d_in, const int* in_sizes, int n_in,
                              void* d_out, int out_size, void* d_ws, size_t ws_size,
                              hipStream_t stream) {
  (void)in_sizes; (void)n_in; (void)out_size; (void)ws_size;
  const float* enc    = (const float*)d_in[0];
  const int*   lens   = (const int*)d_in[1];
  const float* embed  = (const float*)d_in[2];
  const float* W_i    = (const float*)d_in[3];
  const float* W_h    = (const float*)d_in[4];
  const float* b_lstm = (const float*)d_in[5];
  const float* W_enc  = (const float*)d_in[6];
  const float* W_pred = (const float*)d_in[7];
  const float* b_joint= (const float*)d_in[8];
  const float* W_out  = (const float*)d_in[9];
  const float* b_out  = (const float*)d_in[10];
  float* out = (float*)d_out;

  char* ws = (char*)d_ws;
  size_t off = 0;
  auto carve = [&](size_t bytes) -> void* {
    void* p = ws + off;
    off += (bytes + 255) & ~(size_t)255;
    return p;
  };
  unsigned* arrive           = (unsigned*)carve((size_t)NB * ARRS * 4);
  unsigned* go               = (unsigned*)carve((size_t)64 * GOS * 4);
  unsigned long long* kslot  = (unsigned long long*)carve((size_t)51200 * 8);
  unsigned long long* sslot  = (unsigned long long*)carve((size_t)51200 * 8);
  float* h_ring   = (float*)carve((size_t)201 * HRS * 4);
  float* jt_ring  = (float*)carve((size_t)200 * HRS * 4);
  float* Wpred_t  = (float*)carve((size_t)640 * 640 * 4);
  float* Wcat_t   = (float*)carve((size_t)2560 * 1280 * 4);
  float* Wout_t   = (float*)carve((size_t)4097 * 640 * 4);
  float* enc_projB= (float*)carve((size_t)32 * 100 * 640 * 4);

  rnnt_prep<<<2048, 256, 0, stream>>>(
      enc, W_i, W_h, W_pred, W_out, W_enc, b_joint,
      out, Wcat_t, Wpred_t, Wout_t, enc_projB, h_ring, kslot, sslot, arrive, go);
  rnnt_decode<<<NB, 256, 0, stream>>>(
      lens, embed, b_lstm, b_out, out,
      Wcat_t, Wpred_t, Wout_t, enc_projB, h_ring, jt_ring, kslot, sslot,
      arrive, go);
}